// Round 10
// baseline (316.696 us; speedup 1.0000x reference)
//
#include <hip/hip_runtime.h>

#define DM 1024
#define H_ 16
#define DH 64
#define B_ 8
#define S_ 1024

typedef _Float16 half8 __attribute__((ext_vector_type(8)));
typedef _Float16 half4 __attribute__((ext_vector_type(4)));
typedef __fp16 fp16x2 __attribute__((ext_vector_type(2)));
typedef float f32x4 __attribute__((ext_vector_type(4)));
typedef float f32x16 __attribute__((ext_vector_type(16)));
typedef unsigned int uint;

// packed f32x2 -> fp16x2 (single v_cvt_pkrtz_f16_f32)
static __device__ __forceinline__ uint pkrtz(float a, float b) {
    fp16x2 h = __builtin_amdgcn_cvt_pkrtz(a, b);
    return __builtin_bit_cast(uint, h);
}
// v_permlane32_swap_b32 d, s: d.lanes[32:63] <-> s.lanes[0:31]
#define PSWAP(d, s) asm volatile("v_permlane32_swap_b32 %0, %1" : "+v"(d), "+v"(s))

// async global->LDS, 16 B per lane; LDS dest base must be wave-uniform
static __device__ __forceinline__ void gload16(const _Float16* g, _Float16* l) {
    __builtin_amdgcn_global_load_lds(
        (const __attribute__((address_space(1))) unsigned int*)(const void*)g,
        (__attribute__((address_space(3))) unsigned int*)(void*)l,
        16, 0, 0);
}

// split 8 f32 into hi/lo half8
static __device__ __forceinline__ void cvt8(float4 a, float4 b, half8& hv, half8& lv) {
    hv[0] = (_Float16)a.x; lv[0] = (_Float16)(a.x - (float)hv[0]);
    hv[1] = (_Float16)a.y; lv[1] = (_Float16)(a.y - (float)hv[1]);
    hv[2] = (_Float16)a.z; lv[2] = (_Float16)(a.z - (float)hv[2]);
    hv[3] = (_Float16)a.w; lv[3] = (_Float16)(a.w - (float)hv[3]);
    hv[4] = (_Float16)b.x; lv[4] = (_Float16)(b.x - (float)hv[4]);
    hv[5] = (_Float16)b.y; lv[5] = (_Float16)(b.y - (float)hv[5]);
    hv[6] = (_Float16)b.z; lv[6] = (_Float16)(b.z - (float)hv[6]);
    hv[7] = (_Float16)b.w; lv[7] = (_Float16)(b.w - (float)hv[7]);
}

// ---------------------------------------------------------------------------
// Pack projection weights (r9 version, numerics-validated). Rows n=h*64+l.
// WQ/WK hi/lo: 4-chunk XOR aligned to 32-col tiles:
//   phys p holds logical (p&4)|((p&3)^((l>>2)&3)).
// WV: 8-chunk XOR (BK=64 consumer): phys p holds logical p^(l&7).
// ---------------------------------------------------------------------------
__global__ __launch_bounds__(256) void packw_k(
    const float* __restrict__ WQ, const float* __restrict__ WK,
    const float* __restrict__ WV,
    _Float16* __restrict__ wqh, _Float16* __restrict__ wql,
    _Float16* __restrict__ wkh, _Float16* __restrict__ wkl,
    _Float16* __restrict__ wv)
{
    __shared__ __align__(16) _Float16 Lh[64][72];
    __shared__ __align__(16) _Float16 Ll[64][72];
    const int t = threadIdx.x;
    const int kb = blockIdx.x;
    const int h  = blockIdx.y;

    #pragma unroll
    for (int s = 0; s < 3; ++s) {
        const float* W = (s == 0) ? WQ : ((s == 1) ? WK : WV);
        const int krow = t >> 2, lc = t & 3;
        const float* rp = W + (((size_t)h * 1024 + kb * 64 + krow) * 64 + lc * 16);
        #pragma unroll
        for (int q4 = 0; q4 < 4; ++q4) {
            float4 f = ((const float4*)rp)[q4];
            float vv0 = f.x, vv1 = f.y, vv2 = f.z, vv3 = f.w;
            int l0 = lc * 16 + q4 * 4;
            _Float16 h0 = (_Float16)vv0; Lh[l0 + 0][krow] = h0; Ll[l0 + 0][krow] = (_Float16)(vv0 - (float)h0);
            _Float16 h1 = (_Float16)vv1; Lh[l0 + 1][krow] = h1; Ll[l0 + 1][krow] = (_Float16)(vv1 - (float)h1);
            _Float16 h2 = (_Float16)vv2; Lh[l0 + 2][krow] = h2; Ll[l0 + 2][krow] = (_Float16)(vv2 - (float)h2);
            _Float16 h3 = (_Float16)vv3; Lh[l0 + 3][krow] = h3; Ll[l0 + 3][krow] = (_Float16)(vv3 - (float)h3);
        }
        __syncthreads();
        const int l = t >> 2, pc = t & 3;
        #pragma unroll
        for (int hp = 0; hp < 2; ++hp) {
            int p = pc + 4 * hp;
            int lc2 = (s == 2) ? (p ^ (l & 7))
                               : ((p & 4) | ((p & 3) ^ ((l >> 2) & 3)));
            half8 vh = *(const half8*)&Lh[l][lc2 * 8];
            half8 vl = *(const half8*)&Ll[l][lc2 * 8];
            size_t off = (size_t)(h * 64 + l) * DM + kb * 64 + p * 8;
            if (s == 0) { *(half8*)(wqh + off) = vh; *(half8*)(wql + off) = vl; }
            else if (s == 1) { *(half8*)(wkh + off) = vh; *(half8*)(wkl + off) = vl; }
            else { *(half8*)(wv + off) = vh; }
        }
        __syncthreads();
    }
}

// ---------------------------------------------------------------------------
// Pack W_out: already [n][k]; fp16 convert + 8-chunk XOR.
// ---------------------------------------------------------------------------
__global__ __launch_bounds__(256) void packo_k(
    const float* __restrict__ WO, _Float16* __restrict__ wo)
{
    int idx8 = blockIdx.x * 256 + threadIdx.x;
    int n = idx8 >> 7;
    int c = idx8 & 127;
    int p = (c & ~7) | ((c & 7) ^ (n & 7));
    const float* rp = WO + ((size_t)n * DM + c * 8);
    float4 a = ((const float4*)rp)[0];
    float4 b = ((const float4*)rp)[1];
    half8 v;
    v[0] = (_Float16)a.x; v[1] = (_Float16)a.y; v[2] = (_Float16)a.z; v[3] = (_Float16)a.w;
    v[4] = (_Float16)b.x; v[5] = (_Float16)b.y; v[6] = (_Float16)b.z; v[7] = (_Float16)b.w;
    *(half8*)(wo + (size_t)n * DM + p * 8) = v;
}

// ---------------------------------------------------------------------------
// Mask pre-scan (unchanged, validated).
// ---------------------------------------------------------------------------
__global__ __launch_bounds__(256) void scan_k(
    const unsigned char* __restrict__ mask, unsigned char* __restrict__ scan)
{
    __shared__ int s_red[4];
    const int t = threadIdx.x;
    const int q64 = blockIdx.x, k64 = blockIdx.y, b = blockIdx.z;
    uint4 mv = *(const uint4*)(mask + ((size_t)b * S_ + q64 * 64 + (t >> 2)) * S_ + k64 * 64 + (t & 3) * 16);
    int a = (mv.x | mv.y | mv.z | mv.w) != 0;
    unsigned long long bal = __ballot(a);
    if ((t & 63) == 0) s_red[t >> 6] = (bal != 0ull);
    __syncthreads();
    if (t == 0)
        scan[(b * 16 + q64) * 16 + k64] =
            (unsigned char)(s_red[0] | s_red[1] | s_red[2] | s_red[3]);
}

// ---------------------------------------------------------------------------
// Split-precision GEMM (Q,K proj): 256x256 tile, phase-split schedule.
// 512 thr / 8 waves, wave = 128x64 (acc[8][4]). K-tiles of 32, double-buffered
// 128 KB LDS (Ah|Al|Bh|Bl each 2x[256][32]). Per K-tile: 4 phases, each
// {stage-slice for t+1 -> buf^1; 12 ds_read (one C-quadrant); 24 MFMA;
// s_barrier (alignment-only)}; ONE __syncthreads at tile boundary carries all
// correctness (drains gloads + A ds_writes into buf^1 before it's read).
// A: f32 global->reg->cvt->XOR-chunk LDS (slot c^((row>>2)&3), phase-balanced).
// B: gload_lds linear from 4-chunk pre-XOR'd weights; read slot l4g^((row>>2)&3).
// ---------------------------------------------------------------------------
__global__ __launch_bounds__(512) void gemm_split_k(
    const float* __restrict__ A0, const float* __restrict__ A1,
    const _Float16* __restrict__ Bhg0, const _Float16* __restrict__ Blg0,
    const _Float16* __restrict__ Bhg1, const _Float16* __restrict__ Blg1,
    _Float16* __restrict__ Chi0, _Float16* __restrict__ Clo0,
    _Float16* __restrict__ Chi1, _Float16* __restrict__ Clo1)
{
    // 256 blocks: z fixed per XCD parity (one z's 4 MB weights fit that L2).
    const int lid = blockIdx.x + 4 * blockIdx.y + 128 * blockIdx.z;  // 0..255
    const int xcd = lid & 7, j = lid >> 3;                           // j 0..31
    const int z = xcd & 1;
    const int byv = (xcd >> 1) * 8 + (j >> 2);                       // 0..31
    const int bxv = j & 3;                                           // 0..3

    const float* A = z ? A1 : A0;
    const _Float16* Bhg = z ? Bhg1 : Bhg0;
    const _Float16* Blg = z ? Blg1 : Blg0;
    _Float16* Chi = z ? Chi1 : Chi0;
    _Float16* Clo = z ? Clo1 : Clo0;

    // fp16 offsets: Ah 0 | Al 16384 | Bh 32768 | Bl 49152; each 2 bufs x 8192.
    __shared__ __align__(16) _Float16 SM[65536];   // 128 KB

    const int t = threadIdx.x;
    const int lane = t & 63;
    const int w = t >> 6;                // 0..7
    const int wm = (w >> 2) * 128;       // 0 or 128
    const int wn = (w & 3) * 64;         // 0..192
    const int l15 = lane & 15;
    const int l4g = lane >> 4;

    const int bm = byv * 256;
    const int bn = bxv * 256;

    f32x4 acc[8][4] = {};

    // ---- A staging: thread t covers row t>>1, 16-col half (t&1) ----
    const int arow = t >> 1, ahalf = t & 1;
    const float* ap = A + (size_t)(bm + arow) * DM + ahalf * 16;
    float4 ar0, ar1, ar2, ar3;
    auto aload = [&](int KT) {
        ar0 = *(const float4*)(ap + KT * 32 + 0);
        ar1 = *(const float4*)(ap + KT * 32 + 4);
        ar2 = *(const float4*)(ap + KT * 32 + 8);
        ar3 = *(const float4*)(ap + KT * 32 + 12);
    };
    auto awr = [&](int buf) {
        half8 h0, l0, h1, l1;
        cvt8(ar0, ar1, h0, l0);
        cvt8(ar2, ar3, h1, l1);
        const int key = (arow >> 2) & 3;
        const int c0 = ahalf * 2, c1 = ahalf * 2 + 1;
        const int base = buf * 8192 + arow * 32;
        *(half8*)&SM[base + (c0 ^ key) * 8] = h0;
        *(half8*)&SM[base + (c1 ^ key) * 8] = h1;
        *(half8*)&SM[16384 + base + (c0 ^ key) * 8] = l0;
        *(half8*)&SM[16384 + base + (c1 ^ key) * 8] = l1;
    };
    // ---- B staging: per stream 2 gload16/thread (rows w*32 .. w*32+31) ----
    auto bglh = [&](int KT, int buf) {
        #pragma unroll
        for (int jj = 0; jj < 2; ++jj) {
            int rr = w * 32 + jj * 16 + (lane >> 2);
            gload16(Bhg + (size_t)(bn + rr) * DM + KT * 32 + (lane & 3) * 8,
                    &SM[32768 + buf * 8192 + (w * 32 + jj * 16) * 32]);
        }
    };
    auto bgll = [&](int KT, int buf) {
        #pragma unroll
        for (int jj = 0; jj < 2; ++jj) {
            int rr = w * 32 + jj * 16 + (lane >> 2);
            gload16(Blg + (size_t)(bn + rr) * DM + KT * 32 + (lane & 3) * 8,
                    &SM[49152 + buf * 8192 + (w * 32 + jj * 16) * 32]);
        }
    };
    // ---- one C-quadrant: 12 ds_read + 24 MFMA ----
    auto quad = [&](int buf, int qm, int qn) {
        half8 ah[4], al[4], bh[2], bl[2];
        #pragma unroll
        for (int mi = 0; mi < 4; ++mi) {
            int row = wm + qm * 64 + mi * 16 + l15;
            int off = buf * 8192 + row * 32 + (l4g ^ ((row >> 2) & 3)) * 8;
            ah[mi] = *(const half8*)&SM[off];
            al[mi] = *(const half8*)&SM[16384 + off];
        }
        #pragma unroll
        for (int ni = 0; ni < 2; ++ni) {
            int row = wn + qn * 32 + ni * 16 + l15;
            int off = buf * 8192 + row * 32 + (l4g ^ ((row >> 2) & 3)) * 8;
            bh[ni] = *(const half8*)&SM[32768 + off];
            bl[ni] = *(const half8*)&SM[49152 + off];
        }
        __builtin_amdgcn_s_setprio(1);
        #pragma unroll
        for (int mi = 0; mi < 4; ++mi)
            #pragma unroll
            for (int ni = 0; ni < 2; ++ni) {
                f32x4 c = acc[qm * 4 + mi][qn * 2 + ni];
                c = __builtin_amdgcn_mfma_f32_16x16x32_f16(ah[mi], bh[ni], c, 0, 0, 0);
                c = __builtin_amdgcn_mfma_f32_16x16x32_f16(ah[mi], bl[ni], c, 0, 0, 0);
                c = __builtin_amdgcn_mfma_f32_16x16x32_f16(al[mi], bh[ni], c, 0, 0, 0);
                acc[qm * 4 + mi][qn * 2 + ni] = c;
            }
        __builtin_amdgcn_s_setprio(0);
    };

    // prologue: stage tile 0 into buf 0
    aload(0); bglh(0, 0); bgll(0, 0); awr(0);
    __syncthreads();

    for (int kt = 0; kt < 32; ++kt) {
        const int buf = kt & 1, nxt = buf ^ 1;
        const bool pf = (kt < 31);
        // phase 0: issue Bh(t+1) + A f32 loads; compute quadrant (0,0)
        if (pf) { bglh(kt + 1, nxt); aload(kt + 1); }
        quad(buf, 0, 0);
        __builtin_amdgcn_s_barrier();
        // phase 1: issue Bl(t+1); quadrant (0,1)
        if (pf) bgll(kt + 1, nxt);
        quad(buf, 0, 1);
        __builtin_amdgcn_s_barrier();
        // phase 2: cvt + A ds_writes into nxt; quadrant (1,0)
        if (pf) awr(nxt);
        quad(buf, 1, 0);
        __builtin_amdgcn_s_barrier();
        // phase 3: quadrant (1,1); tile boundary (drains gloads + ds_writes)
        quad(buf, 1, 1);
        __syncthreads();
    }

    #pragma unroll
    for (int mi = 0; mi < 8; ++mi)
        #pragma unroll
        for (int ni = 0; ni < 4; ++ni) {
            int col = bn + wn + ni * 16 + l15;
            #pragma unroll
            for (int r = 0; r < 4; ++r) {
                int row = bm + wm + mi * 16 + l4g * 4 + r;
                float val = acc[mi][ni][r];
                _Float16 hv = (_Float16)val;
                Chi[(size_t)row * DM + col] = hv;
                Clo[(size_t)row * DM + col] = (_Float16)(val - (float)hv);
            }
        }
}

// ---------------------------------------------------------------------------
// V projection (r7 validated, unchanged).
// ---------------------------------------------------------------------------
__global__ __launch_bounds__(256) void gemm_v_k(
    const float* __restrict__ A, const _Float16* __restrict__ Bt,
    _Float16* __restrict__ C)
{
    const int lid = blockIdx.x + 8 * blockIdx.y;
    const int xcd = lid & 7, k2 = lid >> 3;
    const int G = xcd * 8 + (k2 >> 3);
    const int bxv = k2 & 7, byv = G;

    __shared__ __align__(16) _Float16 SM[25600];
    _Float16* As  = SM;             // [128][72]
    _Float16* Bsb = SM + 9216;      // 2 x [128][64]

    const int t = threadIdx.x;
    const int lane = t & 63;
    const int w = t >> 6;
    const int wm = (w >> 1) * 64;
    const int wn = (w & 1) * 64;
    const int l15 = lane & 15;
    const int l4g = lane >> 4;

    const int bm = byv * 128;
    const int bn = bxv * 128;

    f32x4 acc[4][4] = {};

    const int arow = t >> 4, ac4 = t & 15;
    float4 ar[8];
    auto aload = [&](int KT) {
        #pragma unroll
        for (int i = 0; i < 8; ++i)
            ar[i] = *(const float4*)(A + (size_t)(bm + arow + 16 * i) * DM + KT * 64 + ac4 * 4);
    };
    auto awr = [&]() {
        #pragma unroll
        for (int i = 0; i < 8; ++i) {
            float4 v = ar[i];
            half4 hv;
            hv[0] = (_Float16)v.x; hv[1] = (_Float16)v.y;
            hv[2] = (_Float16)v.z; hv[3] = (_Float16)v.w;
            *(half4*)&As[(arow + 16 * i) * 72 + ac4 * 4] = hv;
        }
    };
    auto bgl = [&](int KT, int buf) {
        _Float16* Bd = Bsb + buf * 8192;
        #pragma unroll
        for (int jj = 0; jj < 4; ++jj) {
            int rr = w * 32 + jj * 8 + (lane >> 3);
            gload16(Bt + (size_t)(bn + rr) * DM + KT * 64 + (lane & 7) * 8,
                    &Bd[(w * 32 + jj * 8) * 64]);
        }
    };

    aload(0);
    bgl(0, 0);
    for (int kt = 0; kt < 16; ++kt) {
        const _Float16* Bcur = Bsb + (kt & 1) * 8192;
        awr();
        __syncthreads();
        if (kt < 15) { aload(kt + 1); bgl(kt + 1, (kt + 1) & 1); }
        #pragma unroll
        for (int ks = 0; ks < 2; ++ks) {
            half8 a[4], b[4];
            #pragma unroll
            for (int mi = 0; mi < 4; ++mi)
                a[mi] = *(const half8*)&As[(wm + mi * 16 + l15) * 72 + ks * 32 + l4g * 8];
            #pragma unroll
            for (int ni = 0; ni < 4; ++ni) {
                int row = wn + ni * 16 + l15;
                int slot = (ks * 4 + l4g) ^ (l15 & 7);
                b[ni] = *(const half8*)&Bcur[row * 64 + slot * 8];
            }
            #pragma unroll
            for (int mi = 0; mi < 4; ++mi)
                #pragma unroll
                for (int ni = 0; ni < 4; ++ni)
                    acc[mi][ni] = __builtin_amdgcn_mfma_f32_16x16x32_f16(a[mi], b[ni], acc[mi][ni], 0, 0, 0);
        }
        __syncthreads();
    }

    _Float16* Tw = SM + w * 4608;   // [64][72]
    #pragma unroll
    for (int mi = 0; mi < 4; ++mi)
        #pragma unroll
        for (int ni = 0; ni < 4; ++ni)
            #pragma unroll
            for (int r = 0; r < 4; ++r)
                Tw[(ni * 16 + l15) * 72 + mi * 16 + l4g * 4 + r] = (_Float16)acc[mi][ni][r];
    __syncthreads();
    {
        const int mg0 = bm + wm;
        const int b = mg0 >> 10, s0 = mg0 & 1023;
        _Float16* op = C + ((size_t)b * DM + (bn + wn + lane)) * S_ + s0;
        #pragma unroll
        for (int c8 = 0; c8 < 8; ++c8)
            *(half8*)(op + c8 * 8) = *(const half8*)&Tw[lane * 72 + c8 * 8];
    }
}

// ---------------------------------------------------------------------------
// Output projection (r7 validated, unchanged).
// ---------------------------------------------------------------------------
__global__ __launch_bounds__(256) void gemm_out_k(
    const _Float16* __restrict__ A, const _Float16* __restrict__ Bt,
    float* __restrict__ C, const float* __restrict__ bias)
{
    const int lid = blockIdx.x + 8 * blockIdx.y;
    const int xcd = lid & 7, k2 = lid >> 3;
    const int G = xcd * 8 + (k2 >> 3);
    const int bxv = k2 & 7, byv = G;

    __shared__ __align__(16) _Float16 SM[25600];
    _Float16* As  = SM;
    _Float16* Bsb = SM + 9216;

    const int t = threadIdx.x;
    const int lane = t & 63;
    const int w = t >> 6;
    const int wm = (w >> 1) * 64;
    const int wn = (w & 1) * 64;
    const int l15 = lane & 15;
    const int l4g = lane >> 4;

    const int bm = byv * 128;
    const int bn = bxv * 128;

    f32x4 acc[4][4] = {};

    uint4 arr[4];
    auto aload = [&](int KT) {
        #pragma unroll
        for (int i = 0; i < 4; ++i)
            arr[i] = *(const uint4*)(A + (size_t)(bm + (t >> 3) + 32 * i) * DM + KT * 64 + (t & 7) * 8);
    };
    auto awr = [&]() {
        #pragma unroll
        for (int i = 0; i < 4; ++i)
            *(uint4*)&As[((t >> 3) + 32 * i) * 72 + (t & 7) * 8] = arr[i];
    };
    auto bgl = [&](int KT, int buf) {
        _Float16* Bd = Bsb + buf * 8192;
        #pragma unroll
        for (int jj = 0; jj < 4; ++jj) {
            int rr = w * 32 + jj * 8 + (lane >> 3);
            gload16(Bt + (size_t)(bn + rr) * DM + KT * 64 + (lane & 7) * 8,
                    &Bd[(w * 32 + jj * 8) * 64]);
        }
    };

    aload(0);
    bgl(0, 0);
    for (int kt = 0; kt < 16; ++kt) {
        const _Float16* Bcur = Bsb + (kt & 1) * 8192;
        awr();
        __syncthreads();
        if (kt < 15) { aload(kt + 1); bgl(kt + 1, (kt + 1) & 1); }
        #pragma unroll
        for (int ks = 0; ks < 2; ++ks) {
            half8 a[4], b[4];
            #pragma unroll
            for (int mi = 0; mi < 4; ++mi)
                a[mi] = *(const half8*)&As[(wm + mi * 16 + l15) * 72 + ks * 32 + l4g * 8];
            #pragma unroll
            for (int ni = 0; ni < 4; ++ni) {
                int row = wn + ni * 16 + l15;
                int slot = (ks * 4 + l4g) ^ (l15 & 7);
                b[ni] = *(const half8*)&Bcur[row * 64 + slot * 8];
            }
            #pragma unroll
            for (int mi = 0; mi < 4; ++mi)
                #pragma unroll
                for (int ni = 0; ni < 4; ++ni)
                    acc[mi][ni] = __builtin_amdgcn_mfma_f32_16x16x32_f16(a[mi], b[ni], acc[mi][ni], 0, 0, 0);
        }
        __syncthreads();
    }

    #pragma unroll
    for (int mi = 0; mi < 4; ++mi)
        #pragma unroll
        for (int ni = 0; ni < 4; ++ni) {
            int col = bn + wn + ni * 16 + l15;
            #pragma unroll
            for (int r = 0; r < 4; ++r) {
                int row = bm + wm + mi * 16 + l4g * 4 + r;
                C[(size_t)row * DM + col] = acc[mi][ni][r] + bias[col];
            }
        }
}

// ---------------------------------------------------------------------------
// Flash attention — byte-identical to round 7 (validated).
// ---------------------------------------------------------------------------
__global__ __launch_bounds__(256) void attn_k(
    const _Float16* __restrict__ qhg, const _Float16* __restrict__ qlg,
    const _Float16* __restrict__ khg, const _Float16* __restrict__ klg,
    const _Float16* __restrict__ vtg, const unsigned char* __restrict__ maskg,
    const unsigned char* __restrict__ scanp, _Float16* __restrict__ ho)
{
    __shared__ __align__(16) _Float16 Kh[64][72];
    __shared__ __align__(16) _Float16 Kl[64][72];
    __shared__ __align__(16) _Float16 Vt[64][72];

    const int t = threadIdx.x;
    const int lane = t & 63;
    const int w = t >> 6;
    const int l31 = lane & 31;
    const int hi = lane >> 5;

    const int j = blockIdx.y + 16 * blockIdx.z;          // 0..127
    const int head = 16 * blockIdx.x + (j >> 3);         // 0..127
    const int qt = j & 7;
    const int h = head & 15;
    const int b = head >> 4;

    const int colbase = h * DH;
    const int qrow = qt * 128 + w * 32 + l31;

    half8 qfh[4], qfl[4];
    {
        const size_t base = ((size_t)b * S_ + qrow) * DM + colbase;
        #pragma unroll
        for (int ds = 0; ds < 4; ++ds) {
            qfh[ds] = *(const half8*)(qhg + base + ds * 16 + hi * 8);
            qfl[ds] = *(const half8*)(qlg + base + ds * 16 + hi * 8);
        }
    }

    float m_q = -1e30f, ls = 0.0f;
    f32x16 accO0 = {};
    f32x16 accO1 = {};

    const int r0 = t >> 3;
    const int c0 = (t & 7) * 8;
    const _Float16* kph = khg + ((size_t)b * S_) * DM + colbase;
    const _Float16* kpl = klg + ((size_t)b * S_) * DM + colbase;
    const _Float16* vp  = vtg + ((size_t)b * DM + colbase) * S_;
    const unsigned char* sc0 = scanp + (b * 16 + 2 * qt) * 16;
    const unsigned char* sc1 = scanp + (b * 16 + 2 * qt + 1) * 16;

    uint4 akh0, akh1, akl0, akl1, av0, av1;
#define ALOAD(KT) do { \
        akh0 = *(const uint4*)(kph + (size_t)((KT) * 64 + r0) * DM + c0);       \
        akh1 = *(const uint4*)(kph + (size_t)((KT) * 64 + 32 + r0) * DM + c0);  \
        akl0 = *(const uint4*)(kpl + (size_t)((KT) * 64 + r0) * DM + c0);       \
        akl1 = *(const uint4*)(kpl + (size_t)((KT) * 64 + 32 + r0) * DM + c0);  \
        av0  = *(const uint4*)(vp + (size_t)r0 * S_ + (KT) * 64 + c0);          \
        av1  = *(const uint4*)(vp + (size_t)(32 + r0) * S_ + (KT) * 64 + c0);   \
    } while (0)
#define AWRITE() do { \
        *(uint4*)&Kh[r0][c0] = akh0; *(uint4*)&Kh[32 + r0][c0] = akh1; \
        *(uint4*)&Kl[r0][c0] = akl0; *(uint4*)&Kl[32 + r0][c0] = akl1; \
        *(uint4*)&Vt[r0][c0] = av0;  *(uint4*)&Vt[32 + r0][c0] = av1;  \
    } while (0)

    ALOAD(0);
    AWRITE();
    int msk = sc0[0] | sc1[0];

    const float SC = 0.125f * 1.44269504089f;   // scale * log2(e)
    const float THRRAW = 8.0f / SC;             // defer-max threshold (raw)

    for (int kt = 0; kt < 16; ++kt) {
        __syncthreads();
        const int mskcur = msk;
        if (kt < 15) {
            ALOAD(kt + 1);
            msk = sc0[kt + 1] | sc1[kt + 1];
        }

        // ---- QK^T swapped (raw scores) ----
        f32x16 sa0 = {}, sa1 = {};
        __builtin_amdgcn_s_setprio(1);
        #pragma unroll
        for (int ds = 0; ds < 4; ++ds) {
            half8 kh0 = *(const half8*)&Kh[l31][ds * 16 + hi * 8];
            half8 kl0 = *(const half8*)&Kl[l31][ds * 16 + hi * 8];
            half8 kh1 = *(const half8*)&Kh[32 + l31][ds * 16 + hi * 8];
            half8 kl1 = *(const half8*)&Kl[32 + l31][ds * 16 + hi * 8];
            sa0 = __builtin_amdgcn_mfma_f32_32x32x16_f16(kh0, qfh[ds], sa0, 0, 0, 0);
            sa0 = __builtin_amdgcn_mfma_f32_32x32x16_f16(kh0, qfl[ds], sa0, 0, 0, 0);
            sa0 = __builtin_amdgcn_mfma_f32_32x32x16_f16(kl0, qfh[ds], sa0, 0, 0, 0);
            sa1 = __builtin_amdgcn_mfma_f32_32x32x16_f16(kh1, qfh[ds], sa1, 0, 0, 0);
            sa1 = __builtin_amdgcn_mfma_f32_32x32x16_f16(kh1, qfl[ds], sa1, 0, 0, 0);
            sa1 = __builtin_amdgcn_mfma_f32_32x32x16_f16(kl1, qfh[ds], sa1, 0, 0, 0);
        }
        __builtin_amdgcn_s_setprio(0);

        if (mskcur) {   // rare path
            const unsigned char* mrow = maskg + ((size_t)b * S_ + qrow) * S_ + kt * 64;
            #pragma unroll
            for (int e = 0; e < 16; ++e) {
                int kl_ = (e & 3) + 8 * (e >> 2) + 4 * hi;
                if (mrow[kl_]) sa0[e] = -1e9f;
                if (mrow[32 + kl_]) sa1[e] = -1e9f;
            }
        }

        // ---- online softmax, raw domain, q lane-local ----
        float rm = sa0[0];
        #pragma unroll
        for (int e = 1; e < 16; ++e) rm = fmaxf(rm, sa0[e]);
        #pragma unroll
        for (int e = 0; e < 16; ++e) rm = fmaxf(rm, sa1[e]);
        rm = fmaxf(rm, __shfl_xor(rm, 32));
        if (__any(rm > m_q + THRRAW)) {          // T13: rescale only when needed
            const float mn = fmaxf(m_q, rm);
            const float sfac = exp2f((m_q - mn) * SC);
            m_q = mn;
            ls *= sfac;
            #pragma unroll
            for (int e = 0; e < 16; ++e) { accO0[e] *= sfac; accO1[e] *= sfac; }
        }
        const float nmn = -m_q * SC;
        float rs = 0.0f;
        #pragma unroll
        for (int e = 0; e < 16; ++e) { sa0[e] = exp2f(fmaf(sa0[e], SC, nmn)); rs += sa0[e]; }
        #pragma unroll
        for (int e = 0; e < 16; ++e) { sa1[e] = exp2f(fmaf(sa1[e], SC, nmn)); rs += sa1[e]; }
        rs += __shfl_xor(rs, 32);
        ls += rs;

        // ---- P -> A-frags (cvt_pkrtz + permlane32_swap), then PV ----
        half8 pf[4];
        {
            uint c0_ = pkrtz(sa0[0], sa0[1]),  c1_ = pkrtz(sa0[2], sa0[3]);
            uint c2_ = pkrtz(sa0[4], sa0[5]),  c3_ = pkrtz(sa0[6], sa0[7]);
            uint c4_ = pkrtz(sa0[8], sa0[9]),  c5_ = pkrtz(sa0[10], sa0[11]);
            uint c6_ = pkrtz(sa0[12], sa0[13]), c7_ = pkrtz(sa0[14], sa0[15]);
            PSWAP(c0_, c2_); PSWAP(c1_, c3_);
            PSWAP(c4_, c6_); PSWAP(c5_, c7_);
            uint4 u0 = {c0_, c1_, c2_, c3_}, u1 = {c4_, c5_, c6_, c7_};
            pf[0] = __builtin_bit_cast(half8, u0);
            pf[1] = __builtin_bit_cast(half8, u1);
        }
        {
            uint c0_ = pkrtz(sa1[0], sa1[1]),  c1_ = pkrtz(sa1[2], sa1[3]);
            uint c2_ = pkrtz(sa1[4], sa1[5]),  c3_ = pkrtz(sa1[6], sa1[7]);
            uint c4_ = pkrtz(sa1[8], sa1[9]),  c5_ = pkrtz(sa1[10], sa1[11]);
            uint c6_ = pkrtz(sa1[12], sa1[13]), c7_ = pkrtz(sa1[14], sa1[15]);
            PSWAP(c0_, c2_); PSWAP(c1_, c3_);
            PSWAP(c4_, c6_); PSWAP(c5_, c7_);
            uint4 u0 = {c0_, c1_, c2_, c3_}, u1 = {c4_, c5_, c6_, c7_};
            pf[2] = __builtin_bit_cast(half8, u0);
            pf[3] = __builtin_bit_cast(half8, u1);
        }
        __builtin_amdgcn_s_setprio(1);
        #pragma unroll
        for (int kc = 0; kc < 4; ++kc) {
            half8 vf0 = *(const half8*)&Vt[l31][kc * 16 + hi * 8];
            half8 vf1 = *(const half8*)&Vt[32 + l31][kc * 16 + hi * 8];
            accO0 = __builtin_amdgcn_mfma_f32_32x32x16_f16(vf0, pf[kc], accO0, 0, 0, 0);
            accO1 = __builtin_amdgcn_mfma_f32_32x32x16_f16(vf1, pf[kc], accO1, 0, 0, 0);
        }
        __builtin_amdgcn_s_setprio(0);

        __syncthreads();
        if (kt < 15) AWRITE();
    }
#undef ALOAD
#undef AWRITE

    const float inv = 1.0f / ls;
    _Float16* orow = ho + ((size_t)b * S_ + qrow) * DM + colbase;
    #pragma unroll
    for (int g2 = 0; g2 < 4; ++g2) {
        half4 hv0, hv1;
        #pragma unroll
        for (int e = 0; e < 4; ++e) {
            hv0[e] = (_Float16)(accO0[g2 * 4 + e] * inv);
            hv1[e] = (_Float16)(accO1[g2 * 4 + e] * inv);
        }
        *(half4*)(orow + g2 * 8 + hi * 4) = hv0;
        *(half4*)(orow + 32 + g2 * 8 + hi * 4) = hv1;
    }
}

// ---------------------------------------------------------------------------
extern "C" void kernel_launch(void* const* d_in, const int* in_sizes, int n_in,
                              void* d_out, int out_size, void* d_ws, size_t ws_size,
                              hipStream_t stream)
{
    const float* Qs = (const float*)d_in[0];
    const float* Ks = (const float*)d_in[1];
    const float* Vs = (const float*)d_in[2];
    const unsigned char* mask = (const unsigned char*)d_in[3];
    const float* WQ = (const float*)d_in[4];
    const float* WK = (const float*)d_in[5];
    const float* WV = (const float*)d_in[6];
    const float* WO = (const float*)d_in[7];
    const float* bo = (const float*)d_in[8];

    char* ws = (char*)d_ws;
    const size_t MB = 1024 * 1024;
    _Float16* wqh = (_Float16*)(ws + 0 * MB);
    _Float16* wql = (_Float16*)(ws + 2 * MB);
    _Float16* wkh = (_Float16*)(ws + 4 * MB);
    _Float16* wkl = (_Float16*)(ws + 6 * MB);
    _Float16* wv  = (_Float16*)(ws + 8 * MB);
    _Float16* wo  = (_Float16*)(ws + 10 * MB);
    _Float16* qhi = (_Float16*)(ws + 12 * MB);
    _Float16* qlo = (_Float16*)(ws + 28 * MB);
    _Float16* khi = (_Float16*)(ws + 44 * MB);
    _Float16* klo = (_Float16*)(ws + 60 * MB);
    _Float16* vt  = (_Float16*)(ws + 76 * MB);
    _Float16* hh  = (_Float16*)(ws + 92 * MB);
    unsigned char* scan = (unsigned char*)(ws + 108 * MB);

    packw_k<<<dim3(16, 16), 256, 0, stream>>>(WQ, WK, WV, wqh, wql, wkh, wkl, wv);
    packo_k<<<512, 256, 0, stream>>>(WO, wo);
    scan_k<<<dim3(16, 16, 8), 256, 0, stream>>>(mask, scan);

    gemm_split_k<<<dim3(4, 32, 2), 512, 0, stream>>>(
        Qs, Ks, wqh, wql, wkh, wkl, qhi, qlo, khi, klo);

    gemm_v_k<<<dim3(8, 64), 256, 0, stream>>>(Vs, wv, vt);

    attn_k<<<dim3(8, 16, 8), 256, 0, stream>>>(qhi, qlo, khi, klo, vt, mask, scan, hh);

    gemm_out_k<<<dim3(8, 64), 256, 0, stream>>>(hh, wo, (float*)d_out, bo);
}

// Round 11
// 309.009 us; speedup vs baseline: 1.0249x; 1.0249x over previous
//
#include <hip/hip_runtime.h>

#define DM 1024
#define H_ 16
#define DH 64
#define B_ 8
#define S_ 1024

typedef _Float16 half8 __attribute__((ext_vector_type(8)));
typedef _Float16 half4 __attribute__((ext_vector_type(4)));
typedef __fp16 fp16x2 __attribute__((ext_vector_type(2)));
typedef float f32x4 __attribute__((ext_vector_type(4)));
typedef float f32x16 __attribute__((ext_vector_type(16)));
typedef unsigned int uint;

// packed f32x2 -> fp16x2 (single v_cvt_pkrtz_f16_f32)
static __device__ __forceinline__ uint pkrtz(float a, float b) {
    fp16x2 h = __builtin_amdgcn_cvt_pkrtz(a, b);
    return __builtin_bit_cast(uint, h);
}
// v_permlane32_swap_b32 d, s: d.lanes[32:63] <-> s.lanes[0:31]
#define PSWAP(d, s) asm volatile("v_permlane32_swap_b32 %0, %1" : "+v"(d), "+v"(s))

// async global->LDS, 16 B per lane; LDS dest base must be wave-uniform
static __device__ __forceinline__ void gload16(const _Float16* g, _Float16* l) {
    __builtin_amdgcn_global_load_lds(
        (const __attribute__((address_space(1))) unsigned int*)(const void*)g,
        (__attribute__((address_space(3))) unsigned int*)(void*)l,
        16, 0, 0);
}

// ---------------------------------------------------------------------------
// Pack projection weights with LDS transpose (r7-validated). Rows n=h*64+l,
// cols k, fp16 (hi/lo for WQ,WK), 8-chunk XOR: phys p holds logical p^(l&7).
// ---------------------------------------------------------------------------
__global__ __launch_bounds__(256) void packw_k(
    const float* __restrict__ WQ, const float* __restrict__ WK,
    const float* __restrict__ WV,
    _Float16* __restrict__ wqh, _Float16* __restrict__ wql,
    _Float16* __restrict__ wkh, _Float16* __restrict__ wkl,
    _Float16* __restrict__ wv)
{
    __shared__ __align__(16) _Float16 Lh[64][72];
    __shared__ __align__(16) _Float16 Ll[64][72];
    const int t = threadIdx.x;
    const int kb = blockIdx.x;   // k-block of 64
    const int h  = blockIdx.y;   // head

    #pragma unroll
    for (int s = 0; s < 3; ++s) {
        const float* W = (s == 0) ? WQ : ((s == 1) ? WK : WV);
        const int krow = t >> 2, lc = t & 3;
        const float* rp = W + (((size_t)h * 1024 + kb * 64 + krow) * 64 + lc * 16);
        #pragma unroll
        for (int q4 = 0; q4 < 4; ++q4) {
            float4 f = ((const float4*)rp)[q4];
            float vv0 = f.x, vv1 = f.y, vv2 = f.z, vv3 = f.w;
            int l0 = lc * 16 + q4 * 4;
            _Float16 h0 = (_Float16)vv0; Lh[l0 + 0][krow] = h0; Ll[l0 + 0][krow] = (_Float16)(vv0 - (float)h0);
            _Float16 h1 = (_Float16)vv1; Lh[l0 + 1][krow] = h1; Ll[l0 + 1][krow] = (_Float16)(vv1 - (float)h1);
            _Float16 h2 = (_Float16)vv2; Lh[l0 + 2][krow] = h2; Ll[l0 + 2][krow] = (_Float16)(vv2 - (float)h2);
            _Float16 h3 = (_Float16)vv3; Lh[l0 + 3][krow] = h3; Ll[l0 + 3][krow] = (_Float16)(vv3 - (float)h3);
        }
        __syncthreads();
        const int l = t >> 2, pc = t & 3;
        #pragma unroll
        for (int hp = 0; hp < 2; ++hp) {
            int p = pc + 4 * hp;
            int lc2 = p ^ (l & 7);
            half8 vh = *(const half8*)&Lh[l][lc2 * 8];
            half8 vl = *(const half8*)&Ll[l][lc2 * 8];
            size_t off = (size_t)(h * 64 + l) * DM + kb * 64 + p * 8;
            if (s == 0) { *(half8*)(wqh + off) = vh; *(half8*)(wql + off) = vl; }
            else if (s == 1) { *(half8*)(wkh + off) = vh; *(half8*)(wkl + off) = vl; }
            else { *(half8*)(wv + off) = vh; }
        }
        __syncthreads();
    }
}

// ---------------------------------------------------------------------------
// Pack W_out: already [n][k]; fp16 convert + chunk XOR.
// ---------------------------------------------------------------------------
__global__ __launch_bounds__(256) void packo_k(
    const float* __restrict__ WO, _Float16* __restrict__ wo)
{
    int idx8 = blockIdx.x * 256 + threadIdx.x;
    int n = idx8 >> 7;
    int c = idx8 & 127;
    int p = (c & ~7) | ((c & 7) ^ (n & 7));
    const float* rp = WO + ((size_t)n * DM + c * 8);
    float4 a = ((const float4*)rp)[0];
    float4 b = ((const float4*)rp)[1];
    half8 v;
    v[0] = (_Float16)a.x; v[1] = (_Float16)a.y; v[2] = (_Float16)a.z; v[3] = (_Float16)a.w;
    v[4] = (_Float16)b.x; v[5] = (_Float16)b.y; v[6] = (_Float16)b.z; v[7] = (_Float16)b.w;
    *(half8*)(wo + (size_t)n * DM + p * 8) = v;
}

// ---------------------------------------------------------------------------
// Mask pre-scan (unchanged, validated).
// ---------------------------------------------------------------------------
__global__ __launch_bounds__(256) void scan_k(
    const unsigned char* __restrict__ mask, unsigned char* __restrict__ scan)
{
    __shared__ int s_red[4];
    const int t = threadIdx.x;
    const int q64 = blockIdx.x, k64 = blockIdx.y, b = blockIdx.z;
    uint4 mv = *(const uint4*)(mask + ((size_t)b * S_ + q64 * 64 + (t >> 2)) * S_ + k64 * 64 + (t & 3) * 16);
    int a = (mv.x | mv.y | mv.z | mv.w) != 0;
    unsigned long long bal = __ballot(a);
    if ((t & 63) == 0) s_red[t >> 6] = (bal != 0ull);
    __syncthreads();
    if (t == 0)
        scan[(b * 16 + q64) * 16 + k64] =
            (unsigned char)(s_red[0] | s_red[1] | s_red[2] | s_red[3]);
}

// ---------------------------------------------------------------------------
// Split-precision GEMM (Q,K proj), r7-validated (110 us / 937 TF):
// 512 threads / 8 waves, wave = 32x64 out. A f32 reg-staged -> hi/lo in
// XOR-chunk LDS [128][64]; B via global_load_lds from 8-chunk pre-XOR'd
// weights. LDS 64 KB -> 2 blocks/CU = 16 waves/CU.
// ---------------------------------------------------------------------------
__global__ __launch_bounds__(512) void gemm_split_k(
    const float* __restrict__ A0, const float* __restrict__ A1,
    const _Float16* __restrict__ Bh0, const _Float16* __restrict__ Bl0,
    const _Float16* __restrict__ Bh1, const _Float16* __restrict__ Bl1,
    _Float16* __restrict__ Chi0, _Float16* __restrict__ Clo0,
    _Float16* __restrict__ Chi1, _Float16* __restrict__ Clo1)
{
    const int lid = blockIdx.x + 8 * blockIdx.y + 512 * blockIdx.z;
    const int xcd = lid & 7, k2 = lid >> 3;
    const int G = xcd * 16 + (k2 >> 3);
    const int bxv = k2 & 7, byv = G & 63, z = G >> 6;

    const float* A = z ? A1 : A0;
    const _Float16* Bh = z ? Bh1 : Bh0;
    const _Float16* Bl = z ? Bl1 : Bl0;
    _Float16* Chi = z ? Chi1 : Chi0;
    _Float16* Clo = z ? Clo1 : Clo0;

    __shared__ __align__(16) _Float16 SM[32768];   // 64 KB
    _Float16* Ah  = SM;                 // [128][64] XOR-chunk
    _Float16* Al  = SM + 8192;
    _Float16* Bhs = SM + 16384;         // [128][64] linear dest (pre-XOR'd source)
    _Float16* Bls = SM + 24576;

    const int t = threadIdx.x;
    const int lane = t & 63;
    const int w = t >> 6;               // 0..7
    const int wm = (w >> 1) * 32;
    const int wn = (w & 1) * 64;
    const int l15 = lane & 15;
    const int l4g = lane >> 4;

    const int bm = byv * 128;
    const int bn = bxv * 128;

    f32x4 acc[2][4] = {};

    float4 ar[4];
    auto aload = [&](int KT) {
        #pragma unroll
        for (int i = 0; i < 4; ++i)
            ar[i] = *(const float4*)(A + (size_t)(bm + (t >> 4) + 32 * i) * DM + KT * 64 + (t & 15) * 4);
    };
    auto awr = [&]() {
        #pragma unroll
        for (int i = 0; i < 4; ++i) {
            int row = (t >> 4) + 32 * i;
            int c4 = t & 15;
            float4 v = ar[i];
            half4 hv, lv;
            hv[0] = (_Float16)v.x; lv[0] = (_Float16)(v.x - (float)hv[0]);
            hv[1] = (_Float16)v.y; lv[1] = (_Float16)(v.y - (float)hv[1]);
            hv[2] = (_Float16)v.z; lv[2] = (_Float16)(v.z - (float)hv[2]);
            hv[3] = (_Float16)v.w; lv[3] = (_Float16)(v.w - (float)hv[3]);
            int off = row * 64 + (((c4 >> 1) ^ (row & 7)) * 8) + (c4 & 1) * 4;
            *(half4*)&Ah[off] = hv;
            *(half4*)&Al[off] = lv;
        }
    };
    auto bgl = [&](int KT) {
        #pragma unroll
        for (int jj = 0; jj < 2; ++jj) {
            int rr = w * 16 + jj * 8 + (lane >> 3);
            const size_t so = (size_t)(bn + rr) * DM + KT * 64 + (lane & 7) * 8;
            gload16(Bh + so, &Bhs[(w * 16 + jj * 8) * 64]);
            gload16(Bl + so, &Bls[(w * 16 + jj * 8) * 64]);
        }
    };

    aload(0);
    bgl(0);
    for (int kt = 0; kt < 16; ++kt) {
        awr();
        __syncthreads();                 // A written + B gloads drained
        if (kt < 15) aload(kt + 1);      // prefetch under MFMA
        #pragma unroll
        for (int ks = 0; ks < 2; ++ks) {
            half8 ah[2], al[2], bh[4], bl[4];
            const int slotx = (ks * 4 + l4g);
            #pragma unroll
            for (int mi = 0; mi < 2; ++mi) {
                int r = wm + mi * 16 + l15;
                int off = r * 64 + (slotx ^ (l15 & 7)) * 8;
                ah[mi] = *(const half8*)&Ah[off];
                al[mi] = *(const half8*)&Al[off];
            }
            #pragma unroll
            for (int ni = 0; ni < 4; ++ni) {
                int r = wn + ni * 16 + l15;
                int off = r * 64 + (slotx ^ (l15 & 7)) * 8;
                bh[ni] = *(const half8*)&Bhs[off];
                bl[ni] = *(const half8*)&Bls[off];
            }
            #pragma unroll
            for (int mi = 0; mi < 2; ++mi)
                #pragma unroll
                for (int ni = 0; ni < 4; ++ni) {
                    acc[mi][ni] = __builtin_amdgcn_mfma_f32_16x16x32_f16(ah[mi], bh[ni], acc[mi][ni], 0, 0, 0);
                    acc[mi][ni] = __builtin_amdgcn_mfma_f32_16x16x32_f16(ah[mi], bl[ni], acc[mi][ni], 0, 0, 0);
                    acc[mi][ni] = __builtin_amdgcn_mfma_f32_16x16x32_f16(al[mi], bh[ni], acc[mi][ni], 0, 0, 0);
                }
        }
        __syncthreads();                 // all waves done reading LDS[kt]
        if (kt < 15) bgl(kt + 1);
    }

    #pragma unroll
    for (int mi = 0; mi < 2; ++mi)
        #pragma unroll
        for (int ni = 0; ni < 4; ++ni) {
            int col = bn + wn + ni * 16 + l15;
            #pragma unroll
            for (int r = 0; r < 4; ++r) {
                int row = bm + wm + mi * 16 + l4g * 4 + r;
                float val = acc[mi][ni][r];
                _Float16 hv = (_Float16)val;
                Chi[(size_t)row * DM + col] = hv;
                Clo[(size_t)row * DM + col] = (_Float16)(val - (float)hv);
            }
        }
}

// ---------------------------------------------------------------------------
// V projection (r7-validated, unchanged).
// ---------------------------------------------------------------------------
__global__ __launch_bounds__(256) void gemm_v_k(
    const float* __restrict__ A, const _Float16* __restrict__ Bt,
    _Float16* __restrict__ C)
{
    const int lid = blockIdx.x + 8 * blockIdx.y;
    const int xcd = lid & 7, k2 = lid >> 3;
    const int G = xcd * 8 + (k2 >> 3);
    const int bxv = k2 & 7, byv = G;

    __shared__ __align__(16) _Float16 SM[25600];
    _Float16* As  = SM;             // [128][72]
    _Float16* Bsb = SM + 9216;      // 2 x [128][64]

    const int t = threadIdx.x;
    const int lane = t & 63;
    const int w = t >> 6;
    const int wm = (w >> 1) * 64;
    const int wn = (w & 1) * 64;
    const int l15 = lane & 15;
    const int l4g = lane >> 4;

    const int bm = byv * 128;
    const int bn = bxv * 128;

    f32x4 acc[4][4] = {};

    const int arow = t >> 4, ac4 = t & 15;
    float4 ar[8];
    auto aload = [&](int KT) {
        #pragma unroll
        for (int i = 0; i < 8; ++i)
            ar[i] = *(const float4*)(A + (size_t)(bm + arow + 16 * i) * DM + KT * 64 + ac4 * 4);
    };
    auto awr = [&]() {
        #pragma unroll
        for (int i = 0; i < 8; ++i) {
            float4 v = ar[i];
            half4 hv;
            hv[0] = (_Float16)v.x; hv[1] = (_Float16)v.y;
            hv[2] = (_Float16)v.z; hv[3] = (_Float16)v.w;
            *(half4*)&As[(arow + 16 * i) * 72 + ac4 * 4] = hv;
        }
    };
    auto bgl = [&](int KT, int buf) {
        _Float16* Bd = Bsb + buf * 8192;
        #pragma unroll
        for (int jj = 0; jj < 4; ++jj) {
            int rr = w * 32 + jj * 8 + (lane >> 3);
            gload16(Bt + (size_t)(bn + rr) * DM + KT * 64 + (lane & 7) * 8,
                    &Bd[(w * 32 + jj * 8) * 64]);
        }
    };

    aload(0);
    bgl(0, 0);
    for (int kt = 0; kt < 16; ++kt) {
        const _Float16* Bcur = Bsb + (kt & 1) * 8192;
        awr();
        __syncthreads();
        if (kt < 15) { aload(kt + 1); bgl(kt + 1, (kt + 1) & 1); }
        #pragma unroll
        for (int ks = 0; ks < 2; ++ks) {
            half8 a[4], b[4];
            #pragma unroll
            for (int mi = 0; mi < 4; ++mi)
                a[mi] = *(const half8*)&As[(wm + mi * 16 + l15) * 72 + ks * 32 + l4g * 8];
            #pragma unroll
            for (int ni = 0; ni < 4; ++ni) {
                int row = wn + ni * 16 + l15;
                int slot = (ks * 4 + l4g) ^ (l15 & 7);
                b[ni] = *(const half8*)&Bcur[row * 64 + slot * 8];
            }
            #pragma unroll
            for (int mi = 0; mi < 4; ++mi)
                #pragma unroll
                for (int ni = 0; ni < 4; ++ni)
                    acc[mi][ni] = __builtin_amdgcn_mfma_f32_16x16x32_f16(a[mi], b[ni], acc[mi][ni], 0, 0, 0);
        }
        __syncthreads();
    }

    _Float16* Tw = SM + w * 4608;   // [64][72]
    #pragma unroll
    for (int mi = 0; mi < 4; ++mi)
        #pragma unroll
        for (int ni = 0; ni < 4; ++ni)
            #pragma unroll
            for (int r = 0; r < 4; ++r)
                Tw[(ni * 16 + l15) * 72 + mi * 16 + l4g * 4 + r] = (_Float16)acc[mi][ni][r];
    __syncthreads();
    {
        const int mg0 = bm + wm;
        const int b = mg0 >> 10, s0 = mg0 & 1023;
        _Float16* op = C + ((size_t)b * DM + (bn + wn + lane)) * S_ + s0;
        #pragma unroll
        for (int c8 = 0; c8 < 8; ++c8)
            *(half8*)(op + c8 * 8) = *(const half8*)&Tw[lane * 72 + c8 * 8];
    }
}

// ---------------------------------------------------------------------------
// Output projection (r7-validated, unchanged).
// ---------------------------------------------------------------------------
__global__ __launch_bounds__(256) void gemm_out_k(
    const _Float16* __restrict__ A, const _Float16* __restrict__ Bt,
    float* __restrict__ C, const float* __restrict__ bias)
{
    const int lid = blockIdx.x + 8 * blockIdx.y;
    const int xcd = lid & 7, k2 = lid >> 3;
    const int G = xcd * 8 + (k2 >> 3);
    const int bxv = k2 & 7, byv = G;

    __shared__ __align__(16) _Float16 SM[25600];
    _Float16* As  = SM;
    _Float16* Bsb = SM + 9216;

    const int t = threadIdx.x;
    const int lane = t & 63;
    const int w = t >> 6;
    const int wm = (w >> 1) * 64;
    const int wn = (w & 1) * 64;
    const int l15 = lane & 15;
    const int l4g = lane >> 4;

    const int bm = byv * 128;
    const int bn = bxv * 128;

    f32x4 acc[4][4] = {};

    uint4 arr[4];
    auto aload = [&](int KT) {
        #pragma unroll
        for (int i = 0; i < 4; ++i)
            arr[i] = *(const uint4*)(A + (size_t)(bm + (t >> 3) + 32 * i) * DM + KT * 64 + (t & 7) * 8);
    };
    auto awr = [&]() {
        #pragma unroll
        for (int i = 0; i < 4; ++i)
            *(uint4*)&As[((t >> 3) + 32 * i) * 72 + (t & 7) * 8] = arr[i];
    };
    auto bgl = [&](int KT, int buf) {
        _Float16* Bd = Bsb + buf * 8192;
        #pragma unroll
        for (int jj = 0; jj < 4; ++jj) {
            int rr = w * 32 + jj * 8 + (lane >> 3);
            gload16(Bt + (size_t)(bn + rr) * DM + KT * 64 + (lane & 7) * 8,
                    &Bd[(w * 32 + jj * 8) * 64]);
        }
    };

    aload(0);
    bgl(0, 0);
    for (int kt = 0; kt < 16; ++kt) {
        const _Float16* Bcur = Bsb + (kt & 1) * 8192;
        awr();
        __syncthreads();
        if (kt < 15) { aload(kt + 1); bgl(kt + 1, (kt + 1) & 1); }
        #pragma unroll
        for (int ks = 0; ks < 2; ++ks) {
            half8 a[4], b[4];
            #pragma unroll
            for (int mi = 0; mi < 4; ++mi)
                a[mi] = *(const half8*)&As[(wm + mi * 16 + l15) * 72 + ks * 32 + l4g * 8];
            #pragma unroll
            for (int ni = 0; ni < 4; ++ni) {
                int row = wn + ni * 16 + l15;
                int slot = (ks * 4 + l4g) ^ (l15 & 7);
                b[ni] = *(const half8*)&Bcur[row * 64 + slot * 8];
            }
            #pragma unroll
            for (int mi = 0; mi < 4; ++mi)
                #pragma unroll
                for (int ni = 0; ni < 4; ++ni)
                    acc[mi][ni] = __builtin_amdgcn_mfma_f32_16x16x32_f16(a[mi], b[ni], acc[mi][ni], 0, 0, 0);
        }
        __syncthreads();
    }

    #pragma unroll
    for (int mi = 0; mi < 4; ++mi)
        #pragma unroll
        for (int ni = 0; ni < 4; ++ni) {
            int col = bn + wn + ni * 16 + l15;
            #pragma unroll
            for (int r = 0; r < 4; ++r) {
                int row = bm + wm + mi * 16 + l4g * 4 + r;
                C[(size_t)row * DM + col] = acc[mi][ni][r] + bias[col];
            }
        }
}

// ---------------------------------------------------------------------------
// Flash attention, r7-validated compute path, widened to 512 threads / 8
// waves (q-tile 256). K/V staging per thread halves (3 uint4/step vs 6);
// same LDS (27.6 KB), same per-wave math, 2 blocks x 8 waves / CU.
// ---------------------------------------------------------------------------
__global__ __launch_bounds__(512) void attn_k(
    const _Float16* __restrict__ qhg, const _Float16* __restrict__ qlg,
    const _Float16* __restrict__ khg, const _Float16* __restrict__ klg,
    const _Float16* __restrict__ vtg, const unsigned char* __restrict__ maskg,
    const unsigned char* __restrict__ scanp, _Float16* __restrict__ ho)
{
    __shared__ __align__(16) _Float16 Kh[64][72];
    __shared__ __align__(16) _Float16 Kl[64][72];
    __shared__ __align__(16) _Float16 Vt[64][72];

    const int t = threadIdx.x;
    const int lane = t & 63;
    const int w = t >> 6;                // 0..7
    const int l31 = lane & 31;
    const int hi = lane >> 5;

    // XCD swizzle: 16 heads per XCD, 4 q-tiles each.
    const int j = blockIdx.y + 8 * blockIdx.z;           // 0..63
    const int head = 16 * blockIdx.x + (j >> 2);         // 0..127
    const int qt = j & 3;
    const int h = head & 15;
    const int b = head >> 4;

    const int colbase = h * DH;
    const int qrow = qt * 256 + w * 32 + l31;

    half8 qfh[4], qfl[4];
    {
        const size_t base = ((size_t)b * S_ + qrow) * DM + colbase;
        #pragma unroll
        for (int ds = 0; ds < 4; ++ds) {
            qfh[ds] = *(const half8*)(qhg + base + ds * 16 + hi * 8);
            qfl[ds] = *(const half8*)(qlg + base + ds * 16 + hi * 8);
        }
    }

    float m_q = -1e30f, ls = 0.0f;
    f32x16 accO0 = {};
    f32x16 accO1 = {};

    // staging: 512 threads cover 64 rows x 8 chunks, ONE uint4 per stream
    const int r0 = t >> 3;               // 0..63
    const int c0 = (t & 7) * 8;
    const _Float16* kph = khg + ((size_t)b * S_) * DM + colbase;
    const _Float16* kpl = klg + ((size_t)b * S_) * DM + colbase;
    const _Float16* vp  = vtg + ((size_t)b * DM + colbase) * S_;
    const unsigned char* scb = scanp + (b * 16 + 4 * qt) * 16;   // 4 q64 rows

    uint4 akh, akl, av;
#define ALOAD(KT) do { \
        akh = *(const uint4*)(kph + (size_t)((KT) * 64 + r0) * DM + c0);   \
        akl = *(const uint4*)(kpl + (size_t)((KT) * 64 + r0) * DM + c0);   \
        av  = *(const uint4*)(vp + (size_t)r0 * S_ + (KT) * 64 + c0);      \
    } while (0)
#define AWRITE() do { \
        *(uint4*)&Kh[r0][c0] = akh; \
        *(uint4*)&Kl[r0][c0] = akl; \
        *(uint4*)&Vt[r0][c0] = av;  \
    } while (0)
#define SCAN(KT) (scb[KT] | scb[16 + (KT)] | scb[32 + (KT)] | scb[48 + (KT)])

    ALOAD(0);
    AWRITE();
    int msk = SCAN(0);

    const float SC = 0.125f * 1.44269504089f;   // scale * log2(e)
    const float THRRAW = 8.0f / SC;             // defer-max threshold (raw)

    for (int kt = 0; kt < 16; ++kt) {
        __syncthreads();
        const int mskcur = msk;
        if (kt < 15) {
            ALOAD(kt + 1);
            msk = SCAN(kt + 1);
        }

        // ---- QK^T swapped (raw scores) ----
        f32x16 sa0 = {}, sa1 = {};
        __builtin_amdgcn_s_setprio(1);
        #pragma unroll
        for (int ds = 0; ds < 4; ++ds) {
            half8 kh0 = *(const half8*)&Kh[l31][ds * 16 + hi * 8];
            half8 kl0 = *(const half8*)&Kl[l31][ds * 16 + hi * 8];
            half8 kh1 = *(const half8*)&Kh[32 + l31][ds * 16 + hi * 8];
            half8 kl1 = *(const half8*)&Kl[32 + l31][ds * 16 + hi * 8];
            sa0 = __builtin_amdgcn_mfma_f32_32x32x16_f16(kh0, qfh[ds], sa0, 0, 0, 0);
            sa0 = __builtin_amdgcn_mfma_f32_32x32x16_f16(kh0, qfl[ds], sa0, 0, 0, 0);
            sa0 = __builtin_amdgcn_mfma_f32_32x32x16_f16(kl0, qfh[ds], sa0, 0, 0, 0);
            sa1 = __builtin_amdgcn_mfma_f32_32x32x16_f16(kh1, qfh[ds], sa1, 0, 0, 0);
            sa1 = __builtin_amdgcn_mfma_f32_32x32x16_f16(kh1, qfl[ds], sa1, 0, 0, 0);
            sa1 = __builtin_amdgcn_mfma_f32_32x32x16_f16(kl1, qfh[ds], sa1, 0, 0, 0);
        }
        __builtin_amdgcn_s_setprio(0);

        if (mskcur) {   // rare path
            const unsigned char* mrow = maskg + ((size_t)b * S_ + qrow) * S_ + kt * 64;
            #pragma unroll
            for (int e = 0; e < 16; ++e) {
                int kl_ = (e & 3) + 8 * (e >> 2) + 4 * hi;
                if (mrow[kl_]) sa0[e] = -1e9f;
                if (mrow[32 + kl_]) sa1[e] = -1e9f;
            }
        }

        // ---- online softmax, raw domain, q lane-local ----
        float rm = sa0[0];
        #pragma unroll
        for (int e = 1; e < 16; ++e) rm = fmaxf(rm, sa0[e]);
        #pragma unroll
        for (int e = 0; e < 16; ++e) rm = fmaxf(rm, sa1[e]);
        rm = fmaxf(rm, __shfl_xor(rm, 32));
        if (__any(rm > m_q + THRRAW)) {          // T13: rescale only when needed
            const float mn = fmaxf(m_q, rm);
            const float sfac = exp2f((m_q - mn) * SC);
            m_q = mn;
            ls *= sfac;
            #pragma unroll
            for (int e = 0; e < 16; ++e) { accO0[e] *= sfac; accO1[e] *= sfac; }
        }
        const float nmn = -m_q * SC;
        float rs = 0.0f;
        #pragma unroll
        for (int e = 0; e < 16; ++e) { sa0[e] = exp2f(fmaf(sa0[e], SC, nmn)); rs += sa0[e]; }
        #pragma unroll
        for (int e = 0; e < 16; ++e) { sa1[e] = exp2f(fmaf(sa1[e], SC, nmn)); rs += sa1[e]; }
        rs += __shfl_xor(rs, 32);
        ls += rs;

        // ---- P -> A-frags (cvt_pkrtz + permlane32_swap), then PV ----
        half8 pf[4];
        {
            uint c0_ = pkrtz(sa0[0], sa0[1]),  c1_ = pkrtz(sa0[2], sa0[3]);
            uint c2_ = pkrtz(sa0[4], sa0[5]),  c3_ = pkrtz(sa0[6], sa0[7]);
            uint c4_ = pkrtz(sa0[8], sa0[9]),  c5_ = pkrtz(sa0[10], sa0[11]);
            uint c6_ = pkrtz(sa0[12], sa0[13]), c7_ = pkrtz(sa0[14], sa0[15]);
            PSWAP(c0_, c2_); PSWAP(c1_, c3_);
            PSWAP(c4_, c6_); PSWAP(c5_, c7_);
            uint4 u0 = {c0_, c1_, c2_, c3_}, u1 = {c4_, c5_, c6_, c7_};
            pf[0] = __builtin_bit_cast(half8, u0);
            pf[1] = __builtin_bit_cast(half8, u1);
        }
        {
            uint c0_ = pkrtz(sa1[0], sa1[1]),  c1_ = pkrtz(sa1[2], sa1[3]);
            uint c2_ = pkrtz(sa1[4], sa1[5]),  c3_ = pkrtz(sa1[6], sa1[7]);
            uint c4_ = pkrtz(sa1[8], sa1[9]),  c5_ = pkrtz(sa1[10], sa1[11]);
            uint c6_ = pkrtz(sa1[12], sa1[13]), c7_ = pkrtz(sa1[14], sa1[15]);
            PSWAP(c0_, c2_); PSWAP(c1_, c3_);
            PSWAP(c4_, c6_); PSWAP(c5_, c7_);
            uint4 u0 = {c0_, c1_, c2_, c3_}, u1 = {c4_, c5_, c6_, c7_};
            pf[2] = __builtin_bit_cast(half8, u0);
            pf[3] = __builtin_bit_cast(half8, u1);
        }
        __builtin_amdgcn_s_setprio(1);
        #pragma unroll
        for (int kc = 0; kc < 4; ++kc) {
            half8 vf0 = *(const half8*)&Vt[l31][kc * 16 + hi * 8];
            half8 vf1 = *(const half8*)&Vt[32 + l31][kc * 16 + hi * 8];
            accO0 = __builtin_amdgcn_mfma_f32_32x32x16_f16(vf0, pf[kc], accO0, 0, 0, 0);
            accO1 = __builtin_amdgcn_mfma_f32_32x32x16_f16(vf1, pf[kc], accO1, 0, 0, 0);
        }
        __builtin_amdgcn_s_setprio(0);

        __syncthreads();
        if (kt < 15) AWRITE();
    }
#undef ALOAD
#undef AWRITE
#undef SCAN

    const float inv = 1.0f / ls;
    _Float16* orow = ho + ((size_t)b * S_ + qrow) * DM + colbase;
    #pragma unroll
    for (int g2 = 0; g2 < 4; ++g2) {
        half4 hv0, hv1;
        #pragma unroll
        for (int e = 0; e < 4; ++e) {
            hv0[e] = (_Float16)(accO0[g2 * 4 + e] * inv);
            hv1[e] = (_Float16)(accO1[g2 * 4 + e] * inv);
        }
        *(half4*)(orow + g2 * 8 + hi * 4) = hv0;
        *(half4*)(orow + 32 + g2 * 8 + hi * 4) = hv1;
    }
}

// ---------------------------------------------------------------------------
extern "C" void kernel_launch(void* const* d_in, const int* in_sizes, int n_in,
                              void* d_out, int out_size, void* d_ws, size_t ws_size,
                              hipStream_t stream)
{
    const float* Qs = (const float*)d_in[0];
    const float* Ks = (const float*)d_in[1];
    const float* Vs = (const float*)d_in[2];
    const unsigned char* mask = (const unsigned char*)d_in[3];
    const float* WQ = (const float*)d_in[4];
    const float* WK = (const float*)d_in[5];
    const float* WV = (const float*)d_in[6];
    const float* WO = (const float*)d_in[7];
    const float* bo = (const float*)d_in[8];

    char* ws = (char*)d_ws;
    const size_t MB = 1024 * 1024;
    _Float16* wqh = (_Float16*)(ws + 0 * MB);
    _Float16* wql = (_Float16*)(ws + 2 * MB);
    _Float16* wkh = (_Float16*)(ws + 4 * MB);
    _Float16* wkl = (_Float16*)(ws + 6 * MB);
    _Float16* wv  = (_Float16*)(ws + 8 * MB);
    _Float16* wo  = (_Float16*)(ws + 10 * MB);
    _Float16* qhi = (_Float16*)(ws + 12 * MB);
    _Float16* qlo = (_Float16*)(ws + 28 * MB);
    _Float16* khi = (_Float16*)(ws + 44 * MB);
    _Float16* klo = (_Float16*)(ws + 60 * MB);
    _Float16* vt  = (_Float16*)(ws + 76 * MB);
    _Float16* hh  = (_Float16*)(ws + 92 * MB);
    unsigned char* scan = (unsigned char*)(ws + 108 * MB);

    packw_k<<<dim3(16, 16), 256, 0, stream>>>(WQ, WK, WV, wqh, wql, wkh, wkl, wv);
    packo_k<<<512, 256, 0, stream>>>(WO, wo);
    scan_k<<<dim3(16, 16, 8), 256, 0, stream>>>(mask, scan);

    gemm_split_k<<<dim3(8, 64, 2), 512, 0, stream>>>(
        Qs, Ks, wqh, wql, wkh, wkl, qhi, qlo, khi, klo);

    gemm_v_k<<<dim3(8, 64), 256, 0, stream>>>(Vs, wv, vt);

    attn_k<<<dim3(8, 8, 8), 512, 0, stream>>>(qhi, qlo, khi, klo, vt, mask, scan, hh);

    gemm_out_k<<<dim3(8, 64), 256, 0, stream>>>(hh, wo, (float*)d_out, bo);
}

// Round 12
// 298.820 us; speedup vs baseline: 1.0598x; 1.0341x over previous
//
#include <hip/hip_runtime.h>

#define DM 1024
#define H_ 16
#define DH 64
#define B_ 8
#define S_ 1024

typedef _Float16 half8 __attribute__((ext_vector_type(8)));
typedef _Float16 half4 __attribute__((ext_vector_type(4)));
typedef __fp16 fp16x2 __attribute__((ext_vector_type(2)));
typedef float f32x4 __attribute__((ext_vector_type(4)));
typedef float f32x16 __attribute__((ext_vector_type(16)));
typedef unsigned int uint;

// packed f32x2 -> fp16x2 (single v_cvt_pkrtz_f16_f32)
static __device__ __forceinline__ uint pkrtz(float a, float b) {
    fp16x2 h = __builtin_amdgcn_cvt_pkrtz(a, b);
    return __builtin_bit_cast(uint, h);
}
// v_permlane32_swap_b32 d, s: d.lanes[32:63] <-> s.lanes[0:31]
#define PSWAP(d, s) asm volatile("v_permlane32_swap_b32 %0, %1" : "+v"(d), "+v"(s))

// async global->LDS, 16 B per lane; LDS dest base must be wave-uniform
static __device__ __forceinline__ void gload16(const _Float16* g, _Float16* l) {
    __builtin_amdgcn_global_load_lds(
        (const __attribute__((address_space(1))) unsigned int*)(const void*)g,
        (__attribute__((address_space(3))) unsigned int*)(void*)l,
        16, 0, 0);
}

// ---------------------------------------------------------------------------
// Fused prep: packw (blocks 0..255) + packo (256..767) + mask scan (768..2815).
// packw: LDS transpose; rows n=h*64+l, cols k, fp16 (hi/lo for WQ,WK),
// 8-chunk XOR: phys p holds logical p^(l&7). packo: fp16 + chunk XOR.
// scan: scan[b][q64][k64] = any(mask in 64x64 tile).
// ---------------------------------------------------------------------------
__global__ __launch_bounds__(256) void prep_k(
    const float* __restrict__ WQ, const float* __restrict__ WK,
    const float* __restrict__ WV, const float* __restrict__ WO,
    const unsigned char* __restrict__ mask,
    _Float16* __restrict__ wqh, _Float16* __restrict__ wql,
    _Float16* __restrict__ wkh, _Float16* __restrict__ wkl,
    _Float16* __restrict__ wv,  _Float16* __restrict__ wo,
    unsigned char* __restrict__ scan)
{
    __shared__ __align__(16) _Float16 Lh[64][72];
    __shared__ __align__(16) _Float16 Ll[64][72];
    __shared__ int s_red[4];
    const int t = threadIdx.x;
    const int blk = blockIdx.x;

    if (blk < 256) {
        const int kb = blk & 15;     // k-block of 64
        const int h  = blk >> 4;     // head
        #pragma unroll
        for (int s = 0; s < 3; ++s) {
            const float* W = (s == 0) ? WQ : ((s == 1) ? WK : WV);
            const int krow = t >> 2, lc = t & 3;
            const float* rp = W + (((size_t)h * 1024 + kb * 64 + krow) * 64 + lc * 16);
            #pragma unroll
            for (int q4 = 0; q4 < 4; ++q4) {
                float4 f = ((const float4*)rp)[q4];
                float vv0 = f.x, vv1 = f.y, vv2 = f.z, vv3 = f.w;
                int l0 = lc * 16 + q4 * 4;
                _Float16 h0 = (_Float16)vv0; Lh[l0 + 0][krow] = h0; Ll[l0 + 0][krow] = (_Float16)(vv0 - (float)h0);
                _Float16 h1 = (_Float16)vv1; Lh[l0 + 1][krow] = h1; Ll[l0 + 1][krow] = (_Float16)(vv1 - (float)h1);
                _Float16 h2 = (_Float16)vv2; Lh[l0 + 2][krow] = h2; Ll[l0 + 2][krow] = (_Float16)(vv2 - (float)h2);
                _Float16 h3 = (_Float16)vv3; Lh[l0 + 3][krow] = h3; Ll[l0 + 3][krow] = (_Float16)(vv3 - (float)h3);
            }
            __syncthreads();
            const int l = t >> 2, pc = t & 3;
            #pragma unroll
            for (int hp = 0; hp < 2; ++hp) {
                int p = pc + 4 * hp;
                int lc2 = p ^ (l & 7);
                half8 vh = *(const half8*)&Lh[l][lc2 * 8];
                half8 vl = *(const half8*)&Ll[l][lc2 * 8];
                size_t off = (size_t)(h * 64 + l) * DM + kb * 64 + p * 8;
                if (s == 0) { *(half8*)(wqh + off) = vh; *(half8*)(wql + off) = vl; }
                else if (s == 1) { *(half8*)(wkh + off) = vh; *(half8*)(wkl + off) = vl; }
                else { *(half8*)(wv + off) = vh; }
            }
            __syncthreads();
        }
    } else if (blk < 768) {
        int idx8 = (blk - 256) * 256 + t;    // 0..131071
        int n = idx8 >> 7;
        int c = idx8 & 127;
        int p = (c & ~7) | ((c & 7) ^ (n & 7));
        const float* rp = WO + ((size_t)n * DM + c * 8);
        float4 a = ((const float4*)rp)[0];
        float4 b = ((const float4*)rp)[1];
        half8 v;
        v[0] = (_Float16)a.x; v[1] = (_Float16)a.y; v[2] = (_Float16)a.z; v[3] = (_Float16)a.w;
        v[4] = (_Float16)b.x; v[5] = (_Float16)b.y; v[6] = (_Float16)b.z; v[7] = (_Float16)b.w;
        *(half8*)(wo + (size_t)n * DM + p * 8) = v;
    } else {
        const int g = blk - 768;             // 0..2047
        const int q64 = g & 15, k64 = (g >> 4) & 15, b = g >> 8;
        uint4 mv = *(const uint4*)(mask + ((size_t)b * S_ + q64 * 64 + (t >> 2)) * S_ + k64 * 64 + (t & 3) * 16);
        int a = (mv.x | mv.y | mv.z | mv.w) != 0;
        unsigned long long bal = __ballot(a);
        if ((t & 63) == 0) s_red[t >> 6] = (bal != 0ull);
        __syncthreads();
        if (t == 0)
            scan[(b * 16 + q64) * 16 + k64] =
                (unsigned char)(s_red[0] | s_red[1] | s_red[2] | s_red[3]);
    }
}

// ---------------------------------------------------------------------------
// Split-precision GEMM (Q,K proj), r7-validated (110 us / 937 TF):
// 512 threads / 8 waves, wave = 32x64 out. A f32 reg-staged -> hi/lo in
// XOR-chunk LDS [128][64]; B via global_load_lds from 8-chunk pre-XOR'd
// weights. LDS 64 KB -> 2 blocks/CU = 16 waves/CU.
// ---------------------------------------------------------------------------
__global__ __launch_bounds__(512) void gemm_split_k(
    const float* __restrict__ A0, const float* __restrict__ A1,
    const _Float16* __restrict__ Bh0, const _Float16* __restrict__ Bl0,
    const _Float16* __restrict__ Bh1, const _Float16* __restrict__ Bl1,
    _Float16* __restrict__ Chi0, _Float16* __restrict__ Clo0,
    _Float16* __restrict__ Chi1, _Float16* __restrict__ Clo1)
{
    const int lid = blockIdx.x + 8 * blockIdx.y + 512 * blockIdx.z;
    const int xcd = lid & 7, k2 = lid >> 3;
    const int G = xcd * 16 + (k2 >> 3);
    const int bxv = k2 & 7, byv = G & 63, z = G >> 6;

    const float* A = z ? A1 : A0;
    const _Float16* Bh = z ? Bh1 : Bh0;
    const _Float16* Bl = z ? Bl1 : Bl0;
    _Float16* Chi = z ? Chi1 : Chi0;
    _Float16* Clo = z ? Clo1 : Clo0;

    __shared__ __align__(16) _Float16 SM[32768];   // 64 KB
    _Float16* Ah  = SM;                 // [128][64] XOR-chunk
    _Float16* Al  = SM + 8192;
    _Float16* Bhs = SM + 16384;         // [128][64] linear dest (pre-XOR'd source)
    _Float16* Bls = SM + 24576;

    const int t = threadIdx.x;
    const int lane = t & 63;
    const int w = t >> 6;               // 0..7
    const int wm = (w >> 1) * 32;
    const int wn = (w & 1) * 64;
    const int l15 = lane & 15;
    const int l4g = lane >> 4;

    const int bm = byv * 128;
    const int bn = bxv * 128;

    f32x4 acc[2][4] = {};

    float4 ar[4];
    auto aload = [&](int KT) {
        #pragma unroll
        for (int i = 0; i < 4; ++i)
            ar[i] = *(const float4*)(A + (size_t)(bm + (t >> 4) + 32 * i) * DM + KT * 64 + (t & 15) * 4);
    };
    auto awr = [&]() {
        #pragma unroll
        for (int i = 0; i < 4; ++i) {
            int row = (t >> 4) + 32 * i;
            int c4 = t & 15;
            float4 v = ar[i];
            half4 hv, lv;
            hv[0] = (_Float16)v.x; lv[0] = (_Float16)(v.x - (float)hv[0]);
            hv[1] = (_Float16)v.y; lv[1] = (_Float16)(v.y - (float)hv[1]);
            hv[2] = (_Float16)v.z; lv[2] = (_Float16)(v.z - (float)hv[2]);
            hv[3] = (_Float16)v.w; lv[3] = (_Float16)(v.w - (float)hv[3]);
            int off = row * 64 + (((c4 >> 1) ^ (row & 7)) * 8) + (c4 & 1) * 4;
            *(half4*)&Ah[off] = hv;
            *(half4*)&Al[off] = lv;
        }
    };
    auto bgl = [&](int KT) {
        #pragma unroll
        for (int jj = 0; jj < 2; ++jj) {
            int rr = w * 16 + jj * 8 + (lane >> 3);
            const size_t so = (size_t)(bn + rr) * DM + KT * 64 + (lane & 7) * 8;
            gload16(Bh + so, &Bhs[(w * 16 + jj * 8) * 64]);
            gload16(Bl + so, &Bls[(w * 16 + jj * 8) * 64]);
        }
    };

    aload(0);
    bgl(0);
    for (int kt = 0; kt < 16; ++kt) {
        awr();
        __syncthreads();                 // A written + B gloads drained
        if (kt < 15) aload(kt + 1);      // prefetch under MFMA
        #pragma unroll
        for (int ks = 0; ks < 2; ++ks) {
            half8 ah[2], al[2], bh[4], bl[4];
            const int slotx = (ks * 4 + l4g);
            #pragma unroll
            for (int mi = 0; mi < 2; ++mi) {
                int r = wm + mi * 16 + l15;
                int off = r * 64 + (slotx ^ (l15 & 7)) * 8;
                ah[mi] = *(const half8*)&Ah[off];
                al[mi] = *(const half8*)&Al[off];
            }
            #pragma unroll
            for (int ni = 0; ni < 4; ++ni) {
                int r = wn + ni * 16 + l15;
                int off = r * 64 + (slotx ^ (l15 & 7)) * 8;
                bh[ni] = *(const half8*)&Bhs[off];
                bl[ni] = *(const half8*)&Bls[off];
            }
            #pragma unroll
            for (int mi = 0; mi < 2; ++mi)
                #pragma unroll
                for (int ni = 0; ni < 4; ++ni) {
                    acc[mi][ni] = __builtin_amdgcn_mfma_f32_16x16x32_f16(ah[mi], bh[ni], acc[mi][ni], 0, 0, 0);
                    acc[mi][ni] = __builtin_amdgcn_mfma_f32_16x16x32_f16(ah[mi], bl[ni], acc[mi][ni], 0, 0, 0);
                    acc[mi][ni] = __builtin_amdgcn_mfma_f32_16x16x32_f16(al[mi], bh[ni], acc[mi][ni], 0, 0, 0);
                }
        }
        __syncthreads();                 // all waves done reading LDS[kt]
        if (kt < 15) bgl(kt + 1);
    }

    #pragma unroll
    for (int mi = 0; mi < 2; ++mi)
        #pragma unroll
        for (int ni = 0; ni < 4; ++ni) {
            int col = bn + wn + ni * 16 + l15;
            #pragma unroll
            for (int r = 0; r < 4; ++r) {
                int row = bm + wm + mi * 16 + l4g * 4 + r;
                float val = acc[mi][ni][r];
                _Float16 hv = (_Float16)val;
                Chi[(size_t)row * DM + col] = hv;
                Clo[(size_t)row * DM + col] = (_Float16)(val - (float)hv);
            }
        }
}

// ---------------------------------------------------------------------------
// V projection (r7-validated, unchanged).
// ---------------------------------------------------------------------------
__global__ __launch_bounds__(256) void gemm_v_k(
    const float* __restrict__ A, const _Float16* __restrict__ Bt,
    _Float16* __restrict__ C)
{
    const int lid = blockIdx.x + 8 * blockIdx.y;
    const int xcd = lid & 7, k2 = lid >> 3;
    const int G = xcd * 8 + (k2 >> 3);
    const int bxv = k2 & 7, byv = G;

    __shared__ __align__(16) _Float16 SM[25600];
    _Float16* As  = SM;             // [128][72]
    _Float16* Bsb = SM + 9216;      // 2 x [128][64]

    const int t = threadIdx.x;
    const int lane = t & 63;
    const int w = t >> 6;
    const int wm = (w >> 1) * 64;
    const int wn = (w & 1) * 64;
    const int l15 = lane & 15;
    const int l4g = lane >> 4;

    const int bm = byv * 128;
    const int bn = bxv * 128;

    f32x4 acc[4][4] = {};

    const int arow = t >> 4, ac4 = t & 15;
    float4 ar[8];
    auto aload = [&](int KT) {
        #pragma unroll
        for (int i = 0; i < 8; ++i)
            ar[i] = *(const float4*)(A + (size_t)(bm + arow + 16 * i) * DM + KT * 64 + ac4 * 4);
    };
    auto awr = [&]() {
        #pragma unroll
        for (int i = 0; i < 8; ++i) {
            float4 v = ar[i];
            half4 hv;
            hv[0] = (_Float16)v.x; hv[1] = (_Float16)v.y;
            hv[2] = (_Float16)v.z; hv[3] = (_Float16)v.w;
            *(half4*)&As[(arow + 16 * i) * 72 + ac4 * 4] = hv;
        }
    };
    auto bgl = [&](int KT, int buf) {
        _Float16* Bd = Bsb + buf * 8192;
        #pragma unroll
        for (int jj = 0; jj < 4; ++jj) {
            int rr = w * 32 + jj * 8 + (lane >> 3);
            gload16(Bt + (size_t)(bn + rr) * DM + KT * 64 + (lane & 7) * 8,
                    &Bd[(w * 32 + jj * 8) * 64]);
        }
    };

    aload(0);
    bgl(0, 0);
    for (int kt = 0; kt < 16; ++kt) {
        const _Float16* Bcur = Bsb + (kt & 1) * 8192;
        awr();
        __syncthreads();
        if (kt < 15) { aload(kt + 1); bgl(kt + 1, (kt + 1) & 1); }
        #pragma unroll
        for (int ks = 0; ks < 2; ++ks) {
            half8 a[4], b[4];
            #pragma unroll
            for (int mi = 0; mi < 4; ++mi)
                a[mi] = *(const half8*)&As[(wm + mi * 16 + l15) * 72 + ks * 32 + l4g * 8];
            #pragma unroll
            for (int ni = 0; ni < 4; ++ni) {
                int row = wn + ni * 16 + l15;
                int slot = (ks * 4 + l4g) ^ (l15 & 7);
                b[ni] = *(const half8*)&Bcur[row * 64 + slot * 8];
            }
            #pragma unroll
            for (int mi = 0; mi < 4; ++mi)
                #pragma unroll
                for (int ni = 0; ni < 4; ++ni)
                    acc[mi][ni] = __builtin_amdgcn_mfma_f32_16x16x32_f16(a[mi], b[ni], acc[mi][ni], 0, 0, 0);
        }
        __syncthreads();
    }

    _Float16* Tw = SM + w * 4608;   // [64][72]
    #pragma unroll
    for (int mi = 0; mi < 4; ++mi)
        #pragma unroll
        for (int ni = 0; ni < 4; ++ni)
            #pragma unroll
            for (int r = 0; r < 4; ++r)
                Tw[(ni * 16 + l15) * 72 + mi * 16 + l4g * 4 + r] = (_Float16)acc[mi][ni][r];
    __syncthreads();
    {
        const int mg0 = bm + wm;
        const int b = mg0 >> 10, s0 = mg0 & 1023;
        _Float16* op = C + ((size_t)b * DM + (bn + wn + lane)) * S_ + s0;
        #pragma unroll
        for (int c8 = 0; c8 < 8; ++c8)
            *(half8*)(op + c8 * 8) = *(const half8*)&Tw[lane * 72 + c8 * 8];
    }
}

// ---------------------------------------------------------------------------
// Output projection (r7-validated, unchanged).
// ---------------------------------------------------------------------------
__global__ __launch_bounds__(256) void gemm_out_k(
    const _Float16* __restrict__ A, const _Float16* __restrict__ Bt,
    float* __restrict__ C, const float* __restrict__ bias)
{
    const int lid = blockIdx.x + 8 * blockIdx.y;
    const int xcd = lid & 7, k2 = lid >> 3;
    const int G = xcd * 8 + (k2 >> 3);
    const int bxv = k2 & 7, byv = G;

    __shared__ __align__(16) _Float16 SM[25600];
    _Float16* As  = SM;
    _Float16* Bsb = SM + 9216;

    const int t = threadIdx.x;
    const int lane = t & 63;
    const int w = t >> 6;
    const int wm = (w >> 1) * 64;
    const int wn = (w & 1) * 64;
    const int l15 = lane & 15;
    const int l4g = lane >> 4;

    const int bm = byv * 128;
    const int bn = bxv * 128;

    f32x4 acc[4][4] = {};

    uint4 arr[4];
    auto aload = [&](int KT) {
        #pragma unroll
        for (int i = 0; i < 4; ++i)
            arr[i] = *(const uint4*)(A + (size_t)(bm + (t >> 3) + 32 * i) * DM + KT * 64 + (t & 7) * 8);
    };
    auto awr = [&]() {
        #pragma unroll
        for (int i = 0; i < 4; ++i)
            *(uint4*)&As[((t >> 3) + 32 * i) * 72 + (t & 7) * 8] = arr[i];
    };
    auto bgl = [&](int KT, int buf) {
        _Float16* Bd = Bsb + buf * 8192;
        #pragma unroll
        for (int jj = 0; jj < 4; ++jj) {
            int rr = w * 32 + jj * 8 + (lane >> 3);
            gload16(Bt + (size_t)(bn + rr) * DM + KT * 64 + (lane & 7) * 8,
                    &Bd[(w * 32 + jj * 8) * 64]);
        }
    };

    aload(0);
    bgl(0, 0);
    for (int kt = 0; kt < 16; ++kt) {
        const _Float16* Bcur = Bsb + (kt & 1) * 8192;
        awr();
        __syncthreads();
        if (kt < 15) { aload(kt + 1); bgl(kt + 1, (kt + 1) & 1); }
        #pragma unroll
        for (int ks = 0; ks < 2; ++ks) {
            half8 a[4], b[4];
            #pragma unroll
            for (int mi = 0; mi < 4; ++mi)
                a[mi] = *(const half8*)&As[(wm + mi * 16 + l15) * 72 + ks * 32 + l4g * 8];
            #pragma unroll
            for (int ni = 0; ni < 4; ++ni) {
                int row = wn + ni * 16 + l15;
                int slot = (ks * 4 + l4g) ^ (l15 & 7);
                b[ni] = *(const half8*)&Bcur[row * 64 + slot * 8];
            }
            #pragma unroll
            for (int mi = 0; mi < 4; ++mi)
                #pragma unroll
                for (int ni = 0; ni < 4; ++ni)
                    acc[mi][ni] = __builtin_amdgcn_mfma_f32_16x16x32_f16(a[mi], b[ni], acc[mi][ni], 0, 0, 0);
        }
        __syncthreads();
    }

    #pragma unroll
    for (int mi = 0; mi < 4; ++mi)
        #pragma unroll
        for (int ni = 0; ni < 4; ++ni) {
            int col = bn + wn + ni * 16 + l15;
            #pragma unroll
            for (int r = 0; r < 4; ++r) {
                int row = bm + wm + mi * 16 + l4g * 4 + r;
                C[(size_t)row * DM + col] = acc[mi][ni][r] + bias[col];
            }
        }
}

// ---------------------------------------------------------------------------
// Flash attention — r7-validated 256-thread version; only change: max
// reduction uses nested-fmaxf triples (fuses to v_max3_f32, exact).
// ---------------------------------------------------------------------------
__global__ __launch_bounds__(256) void attn_k(
    const _Float16* __restrict__ qhg, const _Float16* __restrict__ qlg,
    const _Float16* __restrict__ khg, const _Float16* __restrict__ klg,
    const _Float16* __restrict__ vtg, const unsigned char* __restrict__ maskg,
    const unsigned char* __restrict__ scanp, _Float16* __restrict__ ho)
{
    __shared__ __align__(16) _Float16 Kh[64][72];
    __shared__ __align__(16) _Float16 Kl[64][72];
    __shared__ __align__(16) _Float16 Vt[64][72];

    const int t = threadIdx.x;
    const int lane = t & 63;
    const int w = t >> 6;
    const int l31 = lane & 31;
    const int hi = lane >> 5;

    const int j = blockIdx.y + 16 * blockIdx.z;          // 0..127
    const int head = 16 * blockIdx.x + (j >> 3);         // 0..127
    const int qt = j & 7;
    const int h = head & 15;
    const int b = head >> 4;

    const int colbase = h * DH;
    const int qrow = qt * 128 + w * 32 + l31;

    half8 qfh[4], qfl[4];
    {
        const size_t base = ((size_t)b * S_ + qrow) * DM + colbase;
        #pragma unroll
        for (int ds = 0; ds < 4; ++ds) {
            qfh[ds] = *(const half8*)(qhg + base + ds * 16 + hi * 8);
            qfl[ds] = *(const half8*)(qlg + base + ds * 16 + hi * 8);
        }
    }

    float m_q = -1e30f, ls = 0.0f;
    f32x16 accO0 = {};
    f32x16 accO1 = {};

    const int r0 = t >> 3;
    const int c0 = (t & 7) * 8;
    const _Float16* kph = khg + ((size_t)b * S_) * DM + colbase;
    const _Float16* kpl = klg + ((size_t)b * S_) * DM + colbase;
    const _Float16* vp  = vtg + ((size_t)b * DM + colbase) * S_;
    const unsigned char* sc0 = scanp + (b * 16 + 2 * qt) * 16;
    const unsigned char* sc1 = scanp + (b * 16 + 2 * qt + 1) * 16;

    uint4 akh0, akh1, akl0, akl1, av0, av1;
#define ALOAD(KT) do { \
        akh0 = *(const uint4*)(kph + (size_t)((KT) * 64 + r0) * DM + c0);       \
        akh1 = *(const uint4*)(kph + (size_t)((KT) * 64 + 32 + r0) * DM + c0);  \
        akl0 = *(const uint4*)(kpl + (size_t)((KT) * 64 + r0) * DM + c0);       \
        akl1 = *(const uint4*)(kpl + (size_t)((KT) * 64 + 32 + r0) * DM + c0);  \
        av0  = *(const uint4*)(vp + (size_t)r0 * S_ + (KT) * 64 + c0);          \
        av1  = *(const uint4*)(vp + (size_t)(32 + r0) * S_ + (KT) * 64 + c0);   \
    } while (0)
#define AWRITE() do { \
        *(uint4*)&Kh[r0][c0] = akh0; *(uint4*)&Kh[32 + r0][c0] = akh1; \
        *(uint4*)&Kl[r0][c0] = akl0; *(uint4*)&Kl[32 + r0][c0] = akl1; \
        *(uint4*)&Vt[r0][c0] = av0;  *(uint4*)&Vt[32 + r0][c0] = av1;  \
    } while (0)

    ALOAD(0);
    AWRITE();
    int msk = sc0[0] | sc1[0];

    const float SC = 0.125f * 1.44269504089f;   // scale * log2(e)
    const float THRRAW = 8.0f / SC;             // defer-max threshold (raw)

    for (int kt = 0; kt < 16; ++kt) {
        __syncthreads();
        const int mskcur = msk;
        if (kt < 15) {
            ALOAD(kt + 1);
            msk = sc0[kt + 1] | sc1[kt + 1];
        }

        // ---- QK^T swapped (raw scores) ----
        f32x16 sa0 = {}, sa1 = {};
        __builtin_amdgcn_s_setprio(1);
        #pragma unroll
        for (int ds = 0; ds < 4; ++ds) {
            half8 kh0 = *(const half8*)&Kh[l31][ds * 16 + hi * 8];
            half8 kl0 = *(const half8*)&Kl[l31][ds * 16 + hi * 8];
            half8 kh1 = *(const half8*)&Kh[32 + l31][ds * 16 + hi * 8];
            half8 kl1 = *(const half8*)&Kl[32 + l31][ds * 16 + hi * 8];
            sa0 = __builtin_amdgcn_mfma_f32_32x32x16_f16(kh0, qfh[ds], sa0, 0, 0, 0);
            sa0 = __builtin_amdgcn_mfma_f32_32x32x16_f16(kh0, qfl[ds], sa0, 0, 0, 0);
            sa0 = __builtin_amdgcn_mfma_f32_32x32x16_f16(kl0, qfh[ds], sa0, 0, 0, 0);
            sa1 = __builtin_amdgcn_mfma_f32_32x32x16_f16(kh1, qfh[ds], sa1, 0, 0, 0);
            sa1 = __builtin_amdgcn_mfma_f32_32x32x16_f16(kh1, qfl[ds], sa1, 0, 0, 0);
            sa1 = __builtin_amdgcn_mfma_f32_32x32x16_f16(kl1, qfh[ds], sa1, 0, 0, 0);
        }
        __builtin_amdgcn_s_setprio(0);

        if (mskcur) {   // rare path
            const unsigned char* mrow = maskg + ((size_t)b * S_ + qrow) * S_ + kt * 64;
            #pragma unroll
            for (int e = 0; e < 16; ++e) {
                int kl_ = (e & 3) + 8 * (e >> 2) + 4 * hi;
                if (mrow[kl_]) sa0[e] = -1e9f;
                if (mrow[32 + kl_]) sa1[e] = -1e9f;
            }
        }

        // ---- online softmax, raw domain, q lane-local; max via v_max3 ----
        float rm = fmaxf(sa0[0], sa0[1]);
        #pragma unroll
        for (int e = 2; e < 16; e += 2) rm = fmaxf(fmaxf(rm, sa0[e]), sa0[e + 1]);
        #pragma unroll
        for (int e = 0; e < 16; e += 2) rm = fmaxf(fmaxf(rm, sa1[e]), sa1[e + 1]);
        rm = fmaxf(rm, __shfl_xor(rm, 32));
        if (__any(rm > m_q + THRRAW)) {          // T13: rescale only when needed
            const float mn = fmaxf(m_q, rm);
            const float sfac = exp2f((m_q - mn) * SC);
            m_q = mn;
            ls *= sfac;
            #pragma unroll
            for (int e = 0; e < 16; ++e) { accO0[e] *= sfac; accO1[e] *= sfac; }
        }
        const float nmn = -m_q * SC;
        float rs = 0.0f;
        #pragma unroll
        for (int e = 0; e < 16; ++e) { sa0[e] = exp2f(fmaf(sa0[e], SC, nmn)); rs += sa0[e]; }
        #pragma unroll
        for (int e = 0; e < 16; ++e) { sa1[e] = exp2f(fmaf(sa1[e], SC, nmn)); rs += sa1[e]; }
        rs += __shfl_xor(rs, 32);
        ls += rs;

        // ---- P -> A-frags (cvt_pkrtz + permlane32_swap), then PV ----
        half8 pf[4];
        {
            uint c0_ = pkrtz(sa0[0], sa0[1]),  c1_ = pkrtz(sa0[2], sa0[3]);
            uint c2_ = pkrtz(sa0[4], sa0[5]),  c3_ = pkrtz(sa0[6], sa0[7]);
            uint c4_ = pkrtz(sa0[8], sa0[9]),  c5_ = pkrtz(sa0[10], sa0[11]);
            uint c6_ = pkrtz(sa0[12], sa0[13]), c7_ = pkrtz(sa0[14], sa0[15]);
            PSWAP(c0_, c2_); PSWAP(c1_, c3_);
            PSWAP(c4_, c6_); PSWAP(c5_, c7_);
            uint4 u0 = {c0_, c1_, c2_, c3_}, u1 = {c4_, c5_, c6_, c7_};
            pf[0] = __builtin_bit_cast(half8, u0);
            pf[1] = __builtin_bit_cast(half8, u1);
        }
        {
            uint c0_ = pkrtz(sa1[0], sa1[1]),  c1_ = pkrtz(sa1[2], sa1[3]);
            uint c2_ = pkrtz(sa1[4], sa1[5]),  c3_ = pkrtz(sa1[6], sa1[7]);
            uint c4_ = pkrtz(sa1[8], sa1[9]),  c5_ = pkrtz(sa1[10], sa1[11]);
            uint c6_ = pkrtz(sa1[12], sa1[13]), c7_ = pkrtz(sa1[14], sa1[15]);
            PSWAP(c0_, c2_); PSWAP(c1_, c3_);
            PSWAP(c4_, c6_); PSWAP(c5_, c7_);
            uint4 u0 = {c0_, c1_, c2_, c3_}, u1 = {c4_, c5_, c6_, c7_};
            pf[2] = __builtin_bit_cast(half8, u0);
            pf[3] = __builtin_bit_cast(half8, u1);
        }
        __builtin_amdgcn_s_setprio(1);
        #pragma unroll
        for (int kc = 0; kc < 4; ++kc) {
            half8 vf0 = *(const half8*)&Vt[l31][kc * 16 + hi * 8];
            half8 vf1 = *(const half8*)&Vt[32 + l31][kc * 16 + hi * 8];
            accO0 = __builtin_amdgcn_mfma_f32_32x32x16_f16(vf0, pf[kc], accO0, 0, 0, 0);
            accO1 = __builtin_amdgcn_mfma_f32_32x32x16_f16(vf1, pf[kc], accO1, 0, 0, 0);
        }
        __builtin_amdgcn_s_setprio(0);

        __syncthreads();
        if (kt < 15) AWRITE();
    }
#undef ALOAD
#undef AWRITE

    const float inv = 1.0f / ls;
    _Float16* orow = ho + ((size_t)b * S_ + qrow) * DM + colbase;
    #pragma unroll
    for (int g2 = 0; g2 < 4; ++g2) {
        half4 hv0, hv1;
        #pragma unroll
        for (int e = 0; e < 4; ++e) {
            hv0[e] = (_Float16)(accO0[g2 * 4 + e] * inv);
            hv1[e] = (_Float16)(accO1[g2 * 4 + e] * inv);
        }
        *(half4*)(orow + g2 * 8 + hi * 4) = hv0;
        *(half4*)(orow + 32 + g2 * 8 + hi * 4) = hv1;
    }
}

// ---------------------------------------------------------------------------
extern "C" void kernel_launch(void* const* d_in, const int* in_sizes, int n_in,
                              void* d_out, int out_size, void* d_ws, size_t ws_size,
                              hipStream_t stream)
{
    const float* Qs = (const float*)d_in[0];
    const float* Ks = (const float*)d_in[1];
    const float* Vs = (const float*)d_in[2];
    const unsigned char* mask = (const unsigned char*)d_in[3];
    const float* WQ = (const float*)d_in[4];
    const float* WK = (const float*)d_in[5];
    const float* WV = (const float*)d_in[6];
    const float* WO = (const float*)d_in[7];
    const float* bo = (const float*)d_in[8];

    char* ws = (char*)d_ws;
    const size_t MB = 1024 * 1024;
    _Float16* wqh = (_Float16*)(ws + 0 * MB);
    _Float16* wql = (_Float16*)(ws + 2 * MB);
    _Float16* wkh = (_Float16*)(ws + 4 * MB);
    _Float16* wkl = (_Float16*)(ws + 6 * MB);
    _Float16* wv  = (_Float16*)(ws + 8 * MB);
    _Float16* wo  = (_Float16*)(ws + 10 * MB);
    _Float16* qhi = (_Float16*)(ws + 12 * MB);
    _Float16* qlo = (_Float16*)(ws + 28 * MB);
    _Float16* khi = (_Float16*)(ws + 44 * MB);
    _Float16* klo = (_Float16*)(ws + 60 * MB);
    _Float16* vt  = (_Float16*)(ws + 76 * MB);
    _Float16* hh  = (_Float16*)(ws + 92 * MB);
    unsigned char* scan = (unsigned char*)(ws + 108 * MB);

    prep_k<<<2816, 256, 0, stream>>>(WQ, WK, WV, WO, mask,
                                     wqh, wql, wkh, wkl, wv, wo, scan);

    gemm_split_k<<<dim3(8, 64, 2), 512, 0, stream>>>(
        Qs, Ks, wqh, wql, wkh, wkl, qhi, qlo, khi, klo);

    gemm_v_k<<<dim3(8, 64), 256, 0, stream>>>(Vs, wv, vt);

    attn_k<<<dim3(8, 16, 8), 256, 0, stream>>>(qhi, qlo, khi, klo, vt, mask, scan, hh);

    gemm_out_k<<<dim3(8, 64), 256, 0, stream>>>(hh, wo, (float*)d_out, bo);
}

// Round 13
// 268.314 us; speedup vs baseline: 1.1803x; 1.1137x over previous
//
#include <hip/hip_runtime.h>

#define DM 1024
#define H_ 16
#define DH 64
#define B_ 8
#define S_ 1024

typedef _Float16 half8 __attribute__((ext_vector_type(8)));
typedef _Float16 half4 __attribute__((ext_vector_type(4)));
typedef __fp16 fp16x2 __attribute__((ext_vector_type(2)));
typedef float f32x4 __attribute__((ext_vector_type(4)));
typedef float f32x16 __attribute__((ext_vector_type(16)));
typedef unsigned int uint;

// packed f32x2 -> fp16x2 (single v_cvt_pkrtz_f16_f32)
static __device__ __forceinline__ uint pkrtz(float a, float b) {
    fp16x2 h = __builtin_amdgcn_cvt_pkrtz(a, b);
    return __builtin_bit_cast(uint, h);
}
// v_permlane32_swap_b32 d, s: d.lanes[32:63] <-> s.lanes[0:31]
#define PSWAP(d, s) asm volatile("v_permlane32_swap_b32 %0, %1" : "+v"(d), "+v"(s))

// async global->LDS, 16 B per lane; LDS dest base must be wave-uniform
static __device__ __forceinline__ void gload16(const _Float16* g, _Float16* l) {
    __builtin_amdgcn_global_load_lds(
        (const __attribute__((address_space(1))) unsigned int*)(const void*)g,
        (__attribute__((address_space(3))) unsigned int*)(void*)l,
        16, 0, 0);
}

// ---------------------------------------------------------------------------
// Fused prep: packw (blocks 0..255) + packo (256..767) + mask scan (768..2815).
// packw: LDS transpose; rows n=h*64+l, cols k, fp16 (hi/lo for WQ,WK),
// 8-chunk XOR: phys p holds logical p^(l&7). packo: fp16 + chunk XOR.
// scan: scan[b][q64][k64] = any(mask in 64x64 tile).
// ---------------------------------------------------------------------------
__global__ __launch_bounds__(256) void prep_k(
    const float* __restrict__ WQ, const float* __restrict__ WK,
    const float* __restrict__ WV, const float* __restrict__ WO,
    const unsigned char* __restrict__ mask,
    _Float16* __restrict__ wqh, _Float16* __restrict__ wql,
    _Float16* __restrict__ wkh, _Float16* __restrict__ wkl,
    _Float16* __restrict__ wv,  _Float16* __restrict__ wo,
    unsigned char* __restrict__ scan)
{
    __shared__ __align__(16) _Float16 Lh[64][72];
    __shared__ __align__(16) _Float16 Ll[64][72];
    __shared__ int s_red[4];
    const int t = threadIdx.x;
    const int blk = blockIdx.x;

    if (blk < 256) {
        const int kb = blk & 15;     // k-block of 64
        const int h  = blk >> 4;     // head
        #pragma unroll
        for (int s = 0; s < 3; ++s) {
            const float* W = (s == 0) ? WQ : ((s == 1) ? WK : WV);
            const int krow = t >> 2, lc = t & 3;
            const float* rp = W + (((size_t)h * 1024 + kb * 64 + krow) * 64 + lc * 16);
            #pragma unroll
            for (int q4 = 0; q4 < 4; ++q4) {
                float4 f = ((const float4*)rp)[q4];
                float vv0 = f.x, vv1 = f.y, vv2 = f.z, vv3 = f.w;
                int l0 = lc * 16 + q4 * 4;
                _Float16 h0 = (_Float16)vv0; Lh[l0 + 0][krow] = h0; Ll[l0 + 0][krow] = (_Float16)(vv0 - (float)h0);
                _Float16 h1 = (_Float16)vv1; Lh[l0 + 1][krow] = h1; Ll[l0 + 1][krow] = (_Float16)(vv1 - (float)h1);
                _Float16 h2 = (_Float16)vv2; Lh[l0 + 2][krow] = h2; Ll[l0 + 2][krow] = (_Float16)(vv2 - (float)h2);
                _Float16 h3 = (_Float16)vv3; Lh[l0 + 3][krow] = h3; Ll[l0 + 3][krow] = (_Float16)(vv3 - (float)h3);
            }
            __syncthreads();
            const int l = t >> 2, pc = t & 3;
            #pragma unroll
            for (int hp = 0; hp < 2; ++hp) {
                int p = pc + 4 * hp;
                int lc2 = p ^ (l & 7);
                half8 vh = *(const half8*)&Lh[l][lc2 * 8];
                half8 vl = *(const half8*)&Ll[l][lc2 * 8];
                size_t off = (size_t)(h * 64 + l) * DM + kb * 64 + p * 8;
                if (s == 0) { *(half8*)(wqh + off) = vh; *(half8*)(wql + off) = vl; }
                else if (s == 1) { *(half8*)(wkh + off) = vh; *(half8*)(wkl + off) = vl; }
                else { *(half8*)(wv + off) = vh; }
            }
            __syncthreads();
        }
    } else if (blk < 768) {
        int idx8 = (blk - 256) * 256 + t;    // 0..131071
        int n = idx8 >> 7;
        int c = idx8 & 127;
        int p = (c & ~7) | ((c & 7) ^ (n & 7));
        const float* rp = WO + ((size_t)n * DM + c * 8);
        float4 a = ((const float4*)rp)[0];
        float4 b = ((const float4*)rp)[1];
        half8 v;
        v[0] = (_Float16)a.x; v[1] = (_Float16)a.y; v[2] = (_Float16)a.z; v[3] = (_Float16)a.w;
        v[4] = (_Float16)b.x; v[5] = (_Float16)b.y; v[6] = (_Float16)b.z; v[7] = (_Float16)b.w;
        *(half8*)(wo + (size_t)n * DM + p * 8) = v;
    } else {
        const int g = blk - 768;             // 0..2047
        const int q64 = g & 15, k64 = (g >> 4) & 15, b = g >> 8;
        uint4 mv = *(const uint4*)(mask + ((size_t)b * S_ + q64 * 64 + (t >> 2)) * S_ + k64 * 64 + (t & 3) * 16);
        int a = (mv.x | mv.y | mv.z | mv.w) != 0;
        unsigned long long bal = __ballot(a);
        if ((t & 63) == 0) s_red[t >> 6] = (bal != 0ull);
        __syncthreads();
        if (t == 0)
            scan[(b * 16 + q64) * 16 + k64] =
                (unsigned char)(s_red[0] | s_red[1] | s_red[2] | s_red[3]);
    }
}

// ---------------------------------------------------------------------------
// Split-precision GEMM (Q,K proj) — r7/r12-validated, unchanged.
// ---------------------------------------------------------------------------
__global__ __launch_bounds__(512) void gemm_split_k(
    const float* __restrict__ A0, const float* __restrict__ A1,
    const _Float16* __restrict__ Bh0, const _Float16* __restrict__ Bl0,
    const _Float16* __restrict__ Bh1, const _Float16* __restrict__ Bl1,
    _Float16* __restrict__ Chi0, _Float16* __restrict__ Clo0,
    _Float16* __restrict__ Chi1, _Float16* __restrict__ Clo1)
{
    const int lid = blockIdx.x + 8 * blockIdx.y + 512 * blockIdx.z;
    const int xcd = lid & 7, k2 = lid >> 3;
    const int G = xcd * 16 + (k2 >> 3);
    const int bxv = k2 & 7, byv = G & 63, z = G >> 6;

    const float* A = z ? A1 : A0;
    const _Float16* Bh = z ? Bh1 : Bh0;
    const _Float16* Bl = z ? Bl1 : Bl0;
    _Float16* Chi = z ? Chi1 : Chi0;
    _Float16* Clo = z ? Clo1 : Clo0;

    __shared__ __align__(16) _Float16 SM[32768];   // 64 KB
    _Float16* Ah  = SM;                 // [128][64] XOR-chunk
    _Float16* Al  = SM + 8192;
    _Float16* Bhs = SM + 16384;         // [128][64] linear dest (pre-XOR'd source)
    _Float16* Bls = SM + 24576;

    const int t = threadIdx.x;
    const int lane = t & 63;
    const int w = t >> 6;               // 0..7
    const int wm = (w >> 1) * 32;
    const int wn = (w & 1) * 64;
    const int l15 = lane & 15;
    const int l4g = lane >> 4;

    const int bm = byv * 128;
    const int bn = bxv * 128;

    f32x4 acc[2][4] = {};

    float4 ar[4];
    auto aload = [&](int KT) {
        #pragma unroll
        for (int i = 0; i < 4; ++i)
            ar[i] = *(const float4*)(A + (size_t)(bm + (t >> 4) + 32 * i) * DM + KT * 64 + (t & 15) * 4);
    };
    auto awr = [&]() {
        #pragma unroll
        for (int i = 0; i < 4; ++i) {
            int row = (t >> 4) + 32 * i;
            int c4 = t & 15;
            float4 v = ar[i];
            half4 hv, lv;
            hv[0] = (_Float16)v.x; lv[0] = (_Float16)(v.x - (float)hv[0]);
            hv[1] = (_Float16)v.y; lv[1] = (_Float16)(v.y - (float)hv[1]);
            hv[2] = (_Float16)v.z; lv[2] = (_Float16)(v.z - (float)hv[2]);
            hv[3] = (_Float16)v.w; lv[3] = (_Float16)(v.w - (float)hv[3]);
            int off = row * 64 + (((c4 >> 1) ^ (row & 7)) * 8) + (c4 & 1) * 4;
            *(half4*)&Ah[off] = hv;
            *(half4*)&Al[off] = lv;
        }
    };
    auto bgl = [&](int KT) {
        #pragma unroll
        for (int jj = 0; jj < 2; ++jj) {
            int rr = w * 16 + jj * 8 + (lane >> 3);
            const size_t so = (size_t)(bn + rr) * DM + KT * 64 + (lane & 7) * 8;
            gload16(Bh + so, &Bhs[(w * 16 + jj * 8) * 64]);
            gload16(Bl + so, &Bls[(w * 16 + jj * 8) * 64]);
        }
    };

    aload(0);
    bgl(0);
    for (int kt = 0; kt < 16; ++kt) {
        awr();
        __syncthreads();                 // A written + B gloads drained
        if (kt < 15) aload(kt + 1);      // prefetch under MFMA
        #pragma unroll
        for (int ks = 0; ks < 2; ++ks) {
            half8 ah[2], al[2], bh[4], bl[4];
            const int slotx = (ks * 4 + l4g);
            #pragma unroll
            for (int mi = 0; mi < 2; ++mi) {
                int r = wm + mi * 16 + l15;
                int off = r * 64 + (slotx ^ (l15 & 7)) * 8;
                ah[mi] = *(const half8*)&Ah[off];
                al[mi] = *(const half8*)&Al[off];
            }
            #pragma unroll
            for (int ni = 0; ni < 4; ++ni) {
                int r = wn + ni * 16 + l15;
                int off = r * 64 + (slotx ^ (l15 & 7)) * 8;
                bh[ni] = *(const half8*)&Bhs[off];
                bl[ni] = *(const half8*)&Bls[off];
            }
            #pragma unroll
            for (int mi = 0; mi < 2; ++mi)
                #pragma unroll
                for (int ni = 0; ni < 4; ++ni) {
                    acc[mi][ni] = __builtin_amdgcn_mfma_f32_16x16x32_f16(ah[mi], bh[ni], acc[mi][ni], 0, 0, 0);
                    acc[mi][ni] = __builtin_amdgcn_mfma_f32_16x16x32_f16(ah[mi], bl[ni], acc[mi][ni], 0, 0, 0);
                    acc[mi][ni] = __builtin_amdgcn_mfma_f32_16x16x32_f16(al[mi], bh[ni], acc[mi][ni], 0, 0, 0);
                }
        }
        __syncthreads();                 // all waves done reading LDS[kt]
        if (kt < 15) bgl(kt + 1);
    }

    #pragma unroll
    for (int mi = 0; mi < 2; ++mi)
        #pragma unroll
        for (int ni = 0; ni < 4; ++ni) {
            int col = bn + wn + ni * 16 + l15;
            #pragma unroll
            for (int r = 0; r < 4; ++r) {
                int row = bm + wm + mi * 16 + l4g * 4 + r;
                float val = acc[mi][ni][r];
                _Float16 hv = (_Float16)val;
                Chi[(size_t)row * DM + col] = hv;
                Clo[(size_t)row * DM + col] = (_Float16)(val - (float)hv);
            }
        }
}

// ---------------------------------------------------------------------------
// V projection (r7-validated, unchanged).
// ---------------------------------------------------------------------------
__global__ __launch_bounds__(256) void gemm_v_k(
    const float* __restrict__ A, const _Float16* __restrict__ Bt,
    _Float16* __restrict__ C)
{
    const int lid = blockIdx.x + 8 * blockIdx.y;
    const int xcd = lid & 7, k2 = lid >> 3;
    const int G = xcd * 8 + (k2 >> 3);
    const int bxv = k2 & 7, byv = G;

    __shared__ __align__(16) _Float16 SM[25600];
    _Float16* As  = SM;             // [128][72]
    _Float16* Bsb = SM + 9216;      // 2 x [128][64]

    const int t = threadIdx.x;
    const int lane = t & 63;
    const int w = t >> 6;
    const int wm = (w >> 1) * 64;
    const int wn = (w & 1) * 64;
    const int l15 = lane & 15;
    const int l4g = lane >> 4;

    const int bm = byv * 128;
    const int bn = bxv * 128;

    f32x4 acc[4][4] = {};

    const int arow = t >> 4, ac4 = t & 15;
    float4 ar[8];
    auto aload = [&](int KT) {
        #pragma unroll
        for (int i = 0; i < 8; ++i)
            ar[i] = *(const float4*)(A + (size_t)(bm + arow + 16 * i) * DM + KT * 64 + ac4 * 4);
    };
    auto awr = [&]() {
        #pragma unroll
        for (int i = 0; i < 8; ++i) {
            float4 v = ar[i];
            half4 hv;
            hv[0] = (_Float16)v.x; hv[1] = (_Float16)v.y;
            hv[2] = (_Float16)v.z; hv[3] = (_Float16)v.w;
            *(half4*)&As[(arow + 16 * i) * 72 + ac4 * 4] = hv;
        }
    };
    auto bgl = [&](int KT, int buf) {
        _Float16* Bd = Bsb + buf * 8192;
        #pragma unroll
        for (int jj = 0; jj < 4; ++jj) {
            int rr = w * 32 + jj * 8 + (lane >> 3);
            gload16(Bt + (size_t)(bn + rr) * DM + KT * 64 + (lane & 7) * 8,
                    &Bd[(w * 32 + jj * 8) * 64]);
        }
    };

    aload(0);
    bgl(0, 0);
    for (int kt = 0; kt < 16; ++kt) {
        const _Float16* Bcur = Bsb + (kt & 1) * 8192;
        awr();
        __syncthreads();
        if (kt < 15) { aload(kt + 1); bgl(kt + 1, (kt + 1) & 1); }
        #pragma unroll
        for (int ks = 0; ks < 2; ++ks) {
            half8 a[4], b[4];
            #pragma unroll
            for (int mi = 0; mi < 4; ++mi)
                a[mi] = *(const half8*)&As[(wm + mi * 16 + l15) * 72 + ks * 32 + l4g * 8];
            #pragma unroll
            for (int ni = 0; ni < 4; ++ni) {
                int row = wn + ni * 16 + l15;
                int slot = (ks * 4 + l4g) ^ (l15 & 7);
                b[ni] = *(const half8*)&Bcur[row * 64 + slot * 8];
            }
            #pragma unroll
            for (int mi = 0; mi < 4; ++mi)
                #pragma unroll
                for (int ni = 0; ni < 4; ++ni)
                    acc[mi][ni] = __builtin_amdgcn_mfma_f32_16x16x32_f16(a[mi], b[ni], acc[mi][ni], 0, 0, 0);
        }
        __syncthreads();
    }

    _Float16* Tw = SM + w * 4608;   // [64][72]
    #pragma unroll
    for (int mi = 0; mi < 4; ++mi)
        #pragma unroll
        for (int ni = 0; ni < 4; ++ni)
            #pragma unroll
            for (int r = 0; r < 4; ++r)
                Tw[(ni * 16 + l15) * 72 + mi * 16 + l4g * 4 + r] = (_Float16)acc[mi][ni][r];
    __syncthreads();
    {
        const int mg0 = bm + wm;
        const int b = mg0 >> 10, s0 = mg0 & 1023;
        _Float16* op = C + ((size_t)b * DM + (bn + wn + lane)) * S_ + s0;
        #pragma unroll
        for (int c8 = 0; c8 < 8; ++c8)
            *(half8*)(op + c8 * 8) = *(const half8*)&Tw[lane * 72 + c8 * 8];
    }
}

// ---------------------------------------------------------------------------
// Output projection — NEW: both A (hh, pre-XOR'd by attn) and B (wo) staged
// via global_load_lds into double-buffered linear LDS; ONE barrier per
// K-step (stage kt+1 -> buf^1 issued before MFMA on buf; barrier drains
// post-compute). 64 KB LDS -> 2 blocks/CU.
// ---------------------------------------------------------------------------
__global__ __launch_bounds__(256) void gemm_out_k(
    const _Float16* __restrict__ A, const _Float16* __restrict__ Bt,
    float* __restrict__ C, const float* __restrict__ bias)
{
    const int lid = blockIdx.x + 8 * blockIdx.y;
    const int xcd = lid & 7, k2 = lid >> 3;
    const int G = xcd * 8 + (k2 >> 3);
    const int bxv = k2 & 7, byv = G;

    __shared__ __align__(16) _Float16 SM[32768];   // A 2x8192 | B 2x8192

    const int t = threadIdx.x;
    const int lane = t & 63;
    const int w = t >> 6;
    const int wm = (w >> 1) * 64;
    const int wn = (w & 1) * 64;
    const int l15 = lane & 15;
    const int l4g = lane >> 4;

    const int bm = byv * 128;
    const int bn = bxv * 128;

    f32x4 acc[4][4] = {};

    auto stage = [&](int KT, int buf) {
        _Float16* Ad = SM + buf * 8192;
        _Float16* Bd = SM + 16384 + buf * 8192;
        #pragma unroll
        for (int jj = 0; jj < 4; ++jj) {
            int rr = w * 32 + jj * 8 + (lane >> 3);
            const size_t go = (size_t)rr * DM + KT * 64 + (lane & 7) * 8;
            gload16(A + (size_t)bm * DM + go, Ad + (w * 32 + jj * 8) * 64);
            gload16(Bt + (size_t)bn * DM + go, Bd + (w * 32 + jj * 8) * 64);
        }
    };

    stage(0, 0);
    __syncthreads();                     // buf0 staged (vmcnt drained)
    for (int kt = 0; kt < 16; ++kt) {
        const int buf = kt & 1;
        if (kt < 15) stage(kt + 1, buf ^ 1);   // in flight under MFMA
        const _Float16* Ac = SM + buf * 8192;
        const _Float16* Bc = SM + 16384 + buf * 8192;
        #pragma unroll
        for (int ks = 0; ks < 2; ++ks) {
            half8 a[4], b[4];
            const int slotx = ks * 4 + l4g;
            #pragma unroll
            for (int mi = 0; mi < 4; ++mi) {
                int row = wm + mi * 16 + l15;
                a[mi] = *(const half8*)&Ac[row * 64 + ((slotx ^ (l15 & 7)) * 8)];
            }
            #pragma unroll
            for (int ni = 0; ni < 4; ++ni) {
                int row = wn + ni * 16 + l15;
                b[ni] = *(const half8*)&Bc[row * 64 + ((slotx ^ (l15 & 7)) * 8)];
            }
            #pragma unroll
            for (int mi = 0; mi < 4; ++mi)
                #pragma unroll
                for (int ni = 0; ni < 4; ++ni)
                    acc[mi][ni] = __builtin_amdgcn_mfma_f32_16x16x32_f16(a[mi], b[ni], acc[mi][ni], 0, 0, 0);
        }
        __syncthreads();                 // drains kt+1 gloads; frees buf
    }

    #pragma unroll
    for (int mi = 0; mi < 4; ++mi)
        #pragma unroll
        for (int ni = 0; ni < 4; ++ni) {
            int col = bn + wn + ni * 16 + l15;
            #pragma unroll
            for (int r = 0; r < 4; ++r) {
                int row = bm + wm + mi * 16 + l4g * 4 + r;
                C[(size_t)row * DM + col] = acc[mi][ni][r] + bias[col];
            }
        }
}

// ---------------------------------------------------------------------------
// Flash attention — r12-validated compute path with: (1) double-buffered
// K/V LDS + ONE barrier per tile (AWRITE targets the buffer last read in
// iter kt-1; top-of-iter barrier orders all hazards); (2) epilogue writes
// hh pre-XOR-chunk-swizzled (chunk p = (d>>3)^(qrow&7)) for gemm_out gload.
// ---------------------------------------------------------------------------
__global__ __launch_bounds__(256) void attn_k(
    const _Float16* __restrict__ qhg, const _Float16* __restrict__ qlg,
    const _Float16* __restrict__ khg, const _Float16* __restrict__ klg,
    const _Float16* __restrict__ vtg, const unsigned char* __restrict__ maskg,
    const unsigned char* __restrict__ scanp, _Float16* __restrict__ ho)
{
    __shared__ __align__(16) _Float16 KhB[2][64][72];
    __shared__ __align__(16) _Float16 KlB[2][64][72];
    __shared__ __align__(16) _Float16 VtB[2][64][72];

    const int t = threadIdx.x;
    const int lane = t & 63;
    const int w = t >> 6;
    const int l31 = lane & 31;
    const int hi = lane >> 5;

    const int j = blockIdx.y + 16 * blockIdx.z;          // 0..127
    const int head = 16 * blockIdx.x + (j >> 3);         // 0..127
    const int qt = j & 7;
    const int h = head & 15;
    const int b = head >> 4;

    const int colbase = h * DH;
    const int qrow = qt * 128 + w * 32 + l31;

    half8 qfh[4], qfl[4];
    {
        const size_t base = ((size_t)b * S_ + qrow) * DM + colbase;
        #pragma unroll
        for (int ds = 0; ds < 4; ++ds) {
            qfh[ds] = *(const half8*)(qhg + base + ds * 16 + hi * 8);
            qfl[ds] = *(const half8*)(qlg + base + ds * 16 + hi * 8);
        }
    }

    float m_q = -1e30f, ls = 0.0f;
    f32x16 accO0 = {};
    f32x16 accO1 = {};

    const int r0 = t >> 3;
    const int c0 = (t & 7) * 8;
    const _Float16* kph = khg + ((size_t)b * S_) * DM + colbase;
    const _Float16* kpl = klg + ((size_t)b * S_) * DM + colbase;
    const _Float16* vp  = vtg + ((size_t)b * DM + colbase) * S_;
    const unsigned char* sc0 = scanp + (b * 16 + 2 * qt) * 16;
    const unsigned char* sc1 = scanp + (b * 16 + 2 * qt + 1) * 16;

    uint4 akh0, akh1, akl0, akl1, av0, av1;
#define ALOAD(KT) do { \
        akh0 = *(const uint4*)(kph + (size_t)((KT) * 64 + r0) * DM + c0);       \
        akh1 = *(const uint4*)(kph + (size_t)((KT) * 64 + 32 + r0) * DM + c0);  \
        akl0 = *(const uint4*)(kpl + (size_t)((KT) * 64 + r0) * DM + c0);       \
        akl1 = *(const uint4*)(kpl + (size_t)((KT) * 64 + 32 + r0) * DM + c0);  \
        av0  = *(const uint4*)(vp + (size_t)r0 * S_ + (KT) * 64 + c0);          \
        av1  = *(const uint4*)(vp + (size_t)(32 + r0) * S_ + (KT) * 64 + c0);   \
    } while (0)
#define AWRITE(BUF) do { \
        *(uint4*)&KhB[BUF][r0][c0] = akh0; *(uint4*)&KhB[BUF][32 + r0][c0] = akh1; \
        *(uint4*)&KlB[BUF][r0][c0] = akl0; *(uint4*)&KlB[BUF][32 + r0][c0] = akl1; \
        *(uint4*)&VtB[BUF][r0][c0] = av0;  *(uint4*)&VtB[BUF][32 + r0][c0] = av1;  \
    } while (0)

    ALOAD(0);
    AWRITE(0);
    int msk = sc0[0] | sc1[0];

    const float SC = 0.125f * 1.44269504089f;   // scale * log2(e)
    const float THRRAW = 8.0f / SC;             // defer-max threshold (raw)

    for (int kt = 0; kt < 16; ++kt) {
        __syncthreads();                         // buf[cur] visible; buf[cur^1] free
        const int cur = kt & 1;
        const int mskcur = msk;
        if (kt < 15) {
            ALOAD(kt + 1);
            msk = sc0[kt + 1] | sc1[kt + 1];
        }

        // ---- QK^T swapped (raw scores) ----
        f32x16 sa0 = {}, sa1 = {};
        __builtin_amdgcn_s_setprio(1);
        #pragma unroll
        for (int ds = 0; ds < 4; ++ds) {
            half8 kh0 = *(const half8*)&KhB[cur][l31][ds * 16 + hi * 8];
            half8 kl0 = *(const half8*)&KlB[cur][l31][ds * 16 + hi * 8];
            half8 kh1 = *(const half8*)&KhB[cur][32 + l31][ds * 16 + hi * 8];
            half8 kl1 = *(const half8*)&KlB[cur][32 + l31][ds * 16 + hi * 8];
            sa0 = __builtin_amdgcn_mfma_f32_32x32x16_f16(kh0, qfh[ds], sa0, 0, 0, 0);
            sa0 = __builtin_amdgcn_mfma_f32_32x32x16_f16(kh0, qfl[ds], sa0, 0, 0, 0);
            sa0 = __builtin_amdgcn_mfma_f32_32x32x16_f16(kl0, qfh[ds], sa0, 0, 0, 0);
            sa1 = __builtin_amdgcn_mfma_f32_32x32x16_f16(kh1, qfh[ds], sa1, 0, 0, 0);
            sa1 = __builtin_amdgcn_mfma_f32_32x32x16_f16(kh1, qfl[ds], sa1, 0, 0, 0);
            sa1 = __builtin_amdgcn_mfma_f32_32x32x16_f16(kl1, qfh[ds], sa1, 0, 0, 0);
        }
        __builtin_amdgcn_s_setprio(0);

        if (mskcur) {   // rare path
            const unsigned char* mrow = maskg + ((size_t)b * S_ + qrow) * S_ + kt * 64;
            #pragma unroll
            for (int e = 0; e < 16; ++e) {
                int kl_ = (e & 3) + 8 * (e >> 2) + 4 * hi;
                if (mrow[kl_]) sa0[e] = -1e9f;
                if (mrow[32 + kl_]) sa1[e] = -1e9f;
            }
        }

        // ---- online softmax, raw domain, q lane-local; max via v_max3 ----
        float rm = fmaxf(sa0[0], sa0[1]);
        #pragma unroll
        for (int e = 2; e < 16; e += 2) rm = fmaxf(fmaxf(rm, sa0[e]), sa0[e + 1]);
        #pragma unroll
        for (int e = 0; e < 16; e += 2) rm = fmaxf(fmaxf(rm, sa1[e]), sa1[e + 1]);
        rm = fmaxf(rm, __shfl_xor(rm, 32));
        if (__any(rm > m_q + THRRAW)) {          // T13: rescale only when needed
            const float mn = fmaxf(m_q, rm);
            const float sfac = exp2f((m_q - mn) * SC);
            m_q = mn;
            ls *= sfac;
            #pragma unroll
            for (int e = 0; e < 16; ++e) { accO0[e] *= sfac; accO1[e] *= sfac; }
        }
        const float nmn = -m_q * SC;
        float rs = 0.0f;
        #pragma unroll
        for (int e = 0; e < 16; ++e) { sa0[e] = exp2f(fmaf(sa0[e], SC, nmn)); rs += sa0[e]; }
        #pragma unroll
        for (int e = 0; e < 16; ++e) { sa1[e] = exp2f(fmaf(sa1[e], SC, nmn)); rs += sa1[e]; }
        rs += __shfl_xor(rs, 32);
        ls += rs;

        // ---- P -> A-frags (cvt_pkrtz + permlane32_swap), then PV ----
        half8 pf[4];
        {
            uint c0_ = pkrtz(sa0[0], sa0[1]),  c1_ = pkrtz(sa0[2], sa0[3]);
            uint c2_ = pkrtz(sa0[4], sa0[5]),  c3_ = pkrtz(sa0[6], sa0[7]);
            uint c4_ = pkrtz(sa0[8], sa0[9]),  c5_ = pkrtz(sa0[10], sa0[11]);
            uint c6_ = pkrtz(sa0[12], sa0[13]), c7_ = pkrtz(sa0[14], sa0[15]);
            PSWAP(c0_, c2_); PSWAP(c1_, c3_);
            PSWAP(c4_, c6_); PSWAP(c5_, c7_);
            uint4 u0 = {c0_, c1_, c2_, c3_}, u1 = {c4_, c5_, c6_, c7_};
            pf[0] = __builtin_bit_cast(half8, u0);
            pf[1] = __builtin_bit_cast(half8, u1);
        }
        {
            uint c0_ = pkrtz(sa1[0], sa1[1]),  c1_ = pkrtz(sa1[2], sa1[3]);
            uint c2_ = pkrtz(sa1[4], sa1[5]),  c3_ = pkrtz(sa1[6], sa1[7]);
            uint c4_ = pkrtz(sa1[8], sa1[9]),  c5_ = pkrtz(sa1[10], sa1[11]);
            uint c6_ = pkrtz(sa1[12], sa1[13]), c7_ = pkrtz(sa1[14], sa1[15]);
            PSWAP(c0_, c2_); PSWAP(c1_, c3_);
            PSWAP(c4_, c6_); PSWAP(c5_, c7_);
            uint4 u0 = {c0_, c1_, c2_, c3_}, u1 = {c4_, c5_, c6_, c7_};
            pf[2] = __builtin_bit_cast(half8, u0);
            pf[3] = __builtin_bit_cast(half8, u1);
        }
        __builtin_amdgcn_s_setprio(1);
        #pragma unroll
        for (int kc = 0; kc < 4; ++kc) {
            half8 vf0 = *(const half8*)&VtB[cur][l31][kc * 16 + hi * 8];
            half8 vf1 = *(const half8*)&VtB[cur][32 + l31][kc * 16 + hi * 8];
            accO0 = __builtin_amdgcn_mfma_f32_32x32x16_f16(vf0, pf[kc], accO0, 0, 0, 0);
            accO1 = __builtin_amdgcn_mfma_f32_32x32x16_f16(vf1, pf[kc], accO1, 0, 0, 0);
        }
        __builtin_amdgcn_s_setprio(0);

        if (kt < 15) AWRITE(cur ^ 1);            // cross-buffer; ordered by next barrier
    }
#undef ALOAD
#undef AWRITE

    // ---- epilogue: O[q][d]/ls written XOR-chunk-swizzled for gemm_out gload ----
    const float inv = 1.0f / ls;
    _Float16* orow = ho + ((size_t)b * S_ + qrow) * DM + colbase;
    const int key = qrow & 7;
    #pragma unroll
    for (int g2 = 0; g2 < 4; ++g2) {
        half4 hv0, hv1;
        #pragma unroll
        for (int e = 0; e < 4; ++e) {
            hv0[e] = (_Float16)(accO0[g2 * 4 + e] * inv);
            hv1[e] = (_Float16)(accO1[g2 * 4 + e] * inv);
        }
        *(half4*)(orow + (g2 ^ key) * 8 + hi * 4) = hv0;         // chunk g2
        *(half4*)(orow + ((4 + g2) ^ key) * 8 + hi * 4) = hv1;   // chunk 4+g2
    }
}

// ---------------------------------------------------------------------------
extern "C" void kernel_launch(void* const* d_in, const int* in_sizes, int n_in,
                              void* d_out, int out_size, void* d_ws, size_t ws_size,
                              hipStream_t stream)
{
    const float* Qs = (const float*)d_in[0];
    const float* Ks = (const float*)d_in[1];
    const float* Vs = (const float*)d_in[2];
    const unsigned char* mask = (const unsigned char*)d_in[3];
    const float* WQ = (const float*)d_in[4];
    const float* WK = (const float*)d_in[5];
    const float* WV = (const float*)d_in[6];
    const float* WO = (const float*)d_in[7];
    const float* bo = (const float*)d_in[8];

    char* ws = (char*)d_ws;
    const size_t MB = 1024 * 1024;
    _Float16* wqh = (_Float16*)(ws + 0 * MB);
    _Float16* wql = (_Float16*)(ws + 2 * MB);
    _Float16* wkh = (_Float16*)(ws + 4 * MB);
    _Float16* wkl = (_Float16*)(ws + 6 * MB);
    _Float16* wv  = (_Float16*)(ws + 8 * MB);
    _Float16* wo  = (_Float16*)(ws + 10 * MB);
    _Float16* qhi = (_Float16*)(ws + 12 * MB);
    _Float16* qlo = (_Float16*)(ws + 28 * MB);
    _Float16* khi = (_Float16*)(ws + 44 * MB);
    _Float16* klo = (_Float16*)(ws + 60 * MB);
    _Float16* vt  = (_Float16*)(ws + 76 * MB);
    _Float16* hh  = (_Float16*)(ws + 92 * MB);
    unsigned char* scan = (unsigned char*)(ws + 108 * MB);

    prep_k<<<2816, 256, 0, stream>>>(WQ, WK, WV, WO, mask,
                                     wqh, wql, wkh, wkl, wv, wo, scan);

    gemm_split_k<<<dim3(8, 64, 2), 512, 0, stream>>>(
        Qs, Ks, wqh, wql, wkh, wkl, qhi, qlo, khi, klo);

    gemm_v_k<<<dim3(8, 64), 256, 0, stream>>>(Vs, wv, vt);

    attn_k<<<dim3(8, 16, 8), 256, 0, stream>>>(qhi, qlo, khi, klo, vt, mask, scan, hh);

    gemm_out_k<<<dim3(8, 64), 256, 0, stream>>>(hh, wo, (float*)d_out, bo);
}

// Round 14
// 261.634 us; speedup vs baseline: 1.2105x; 1.0255x over previous
//
#include <hip/hip_runtime.h>

#define DM 1024
#define H_ 16
#define DH 64
#define B_ 8
#define S_ 1024

typedef _Float16 half8 __attribute__((ext_vector_type(8)));
typedef _Float16 half4 __attribute__((ext_vector_type(4)));
typedef __fp16 fp16x2 __attribute__((ext_vector_type(2)));
typedef float f32x4 __attribute__((ext_vector_type(4)));
typedef float f32x16 __attribute__((ext_vector_type(16)));
typedef unsigned int uint;

// packed f32x2 -> fp16x2 (single v_cvt_pkrtz_f16_f32)
static __device__ __forceinline__ uint pkrtz(float a, float b) {
    fp16x2 h = __builtin_amdgcn_cvt_pkrtz(a, b);
    return __builtin_bit_cast(uint, h);
}
// v_permlane32_swap_b32 d, s: d.lanes[32:63] <-> s.lanes[0:31]
#define PSWAP(d, s) asm volatile("v_permlane32_swap_b32 %0, %1" : "+v"(d), "+v"(s))

// async global->LDS, 16 B per lane; LDS dest base must be wave-uniform
static __device__ __forceinline__ void gload16(const _Float16* g, _Float16* l) {
    __builtin_amdgcn_global_load_lds(
        (const __attribute__((address_space(1))) unsigned int*)(const void*)g,
        (__attribute__((address_space(3))) unsigned int*)(void*)l,
        16, 0, 0);
}

// ---------------------------------------------------------------------------
// Fused prep: packw (blocks 0..255) + packo (256..767) + mask scan (768..2815).
// ---------------------------------------------------------------------------
__global__ __launch_bounds__(256) void prep_k(
    const float* __restrict__ WQ, const float* __restrict__ WK,
    const float* __restrict__ WV, const float* __restrict__ WO,
    const unsigned char* __restrict__ mask,
    _Float16* __restrict__ wqh, _Float16* __restrict__ wql,
    _Float16* __restrict__ wkh, _Float16* __restrict__ wkl,
    _Float16* __restrict__ wv,  _Float16* __restrict__ wo,
    unsigned char* __restrict__ scan)
{
    __shared__ __align__(16) _Float16 Lh[64][72];
    __shared__ __align__(16) _Float16 Ll[64][72];
    __shared__ int s_red[4];
    const int t = threadIdx.x;
    const int blk = blockIdx.x;

    if (blk < 256) {
        const int kb = blk & 15;     // k-block of 64
        const int h  = blk >> 4;     // head
        #pragma unroll
        for (int s = 0; s < 3; ++s) {
            const float* W = (s == 0) ? WQ : ((s == 1) ? WK : WV);
            const int krow = t >> 2, lc = t & 3;
            const float* rp = W + (((size_t)h * 1024 + kb * 64 + krow) * 64 + lc * 16);
            #pragma unroll
            for (int q4 = 0; q4 < 4; ++q4) {
                float4 f = ((const float4*)rp)[q4];
                float vv0 = f.x, vv1 = f.y, vv2 = f.z, vv3 = f.w;
                int l0 = lc * 16 + q4 * 4;
                _Float16 h0 = (_Float16)vv0; Lh[l0 + 0][krow] = h0; Ll[l0 + 0][krow] = (_Float16)(vv0 - (float)h0);
                _Float16 h1 = (_Float16)vv1; Lh[l0 + 1][krow] = h1; Ll[l0 + 1][krow] = (_Float16)(vv1 - (float)h1);
                _Float16 h2 = (_Float16)vv2; Lh[l0 + 2][krow] = h2; Ll[l0 + 2][krow] = (_Float16)(vv2 - (float)h2);
                _Float16 h3 = (_Float16)vv3; Lh[l0 + 3][krow] = h3; Ll[l0 + 3][krow] = (_Float16)(vv3 - (float)h3);
            }
            __syncthreads();
            const int l = t >> 2, pc = t & 3;
            #pragma unroll
            for (int hp = 0; hp < 2; ++hp) {
                int p = pc + 4 * hp;
                int lc2 = p ^ (l & 7);
                half8 vh = *(const half8*)&Lh[l][lc2 * 8];
                half8 vl = *(const half8*)&Ll[l][lc2 * 8];
                size_t off = (size_t)(h * 64 + l) * DM + kb * 64 + p * 8;
                if (s == 0) { *(half8*)(wqh + off) = vh; *(half8*)(wql + off) = vl; }
                else if (s == 1) { *(half8*)(wkh + off) = vh; *(half8*)(wkl + off) = vl; }
                else { *(half8*)(wv + off) = vh; }
            }
            __syncthreads();
        }
    } else if (blk < 768) {
        int idx8 = (blk - 256) * 256 + t;
        int n = idx8 >> 7;
        int c = idx8 & 127;
        int p = (c & ~7) | ((c & 7) ^ (n & 7));
        const float* rp = WO + ((size_t)n * DM + c * 8);
        float4 a = ((const float4*)rp)[0];
        float4 b = ((const float4*)rp)[1];
        half8 v;
        v[0] = (_Float16)a.x; v[1] = (_Float16)a.y; v[2] = (_Float16)a.z; v[3] = (_Float16)a.w;
        v[4] = (_Float16)b.x; v[5] = (_Float16)b.y; v[6] = (_Float16)b.z; v[7] = (_Float16)b.w;
        *(half8*)(wo + (size_t)n * DM + p * 8) = v;
    } else {
        const int g = blk - 768;
        const int q64 = g & 15, k64 = (g >> 4) & 15, b = g >> 8;
        uint4 mv = *(const uint4*)(mask + ((size_t)b * S_ + q64 * 64 + (t >> 2)) * S_ + k64 * 64 + (t & 3) * 16);
        int a = (mv.x | mv.y | mv.z | mv.w) != 0;
        unsigned long long bal = __ballot(a);
        if ((t & 63) == 0) s_red[t >> 6] = (bal != 0ull);
        __syncthreads();
        if (t == 0)
            scan[(b * 16 + q64) * 16 + k64] =
                (unsigned char)(s_red[0] | s_red[1] | s_red[2] | s_red[3]);
    }
}

// ---------------------------------------------------------------------------
// Fused Q/K/V projections, 512 thr / 8 waves, wave = 32x64 out.
// z in {0,1}: split-precision path (r7-validated, byte-equivalent).
// z == 2: V path — same geometry, single fp16 stream, transposed epilogue
// via per-wave [64][34] LDS tile (vt[b][n][s]). V blocks dispatch last ->
// tail-fill split's CUs; their MFMA/VALU co-issues into split's stalls.
// ---------------------------------------------------------------------------
__global__ __launch_bounds__(512) void gemm_qkv_k(
    const float* __restrict__ A0, const float* __restrict__ A1, const float* __restrict__ A2,
    const _Float16* __restrict__ Bh0, const _Float16* __restrict__ Bl0,
    const _Float16* __restrict__ Bh1, const _Float16* __restrict__ Bl1,
    const _Float16* __restrict__ Bv,
    _Float16* __restrict__ Chi0, _Float16* __restrict__ Clo0,
    _Float16* __restrict__ Chi1, _Float16* __restrict__ Clo1,
    _Float16* __restrict__ Cv)
{
    __shared__ __align__(16) _Float16 SM[32768];   // 64 KB

    const int t = threadIdx.x;
    const int lane = t & 63;
    const int w = t >> 6;               // 0..7
    const int wm = (w >> 1) * 32;
    const int wn = (w & 1) * 64;
    const int l15 = lane & 15;
    const int l4g = lane >> 4;

    const int lid = blockIdx.x + 8 * blockIdx.y + 512 * blockIdx.z;

    if (lid < 1024) {
        // ================= split-precision Q/K path =================
        const int xcd = lid & 7, k2 = lid >> 3;
        const int G = xcd * 16 + (k2 >> 3);
        const int bxv = k2 & 7, byv = G & 63, z = G >> 6;

        const float* A = z ? A1 : A0;
        const _Float16* Bh = z ? Bh1 : Bh0;
        const _Float16* Bl = z ? Bl1 : Bl0;
        _Float16* Chi = z ? Chi1 : Chi0;
        _Float16* Clo = z ? Clo1 : Clo0;

        _Float16* Ah  = SM;                 // [128][64] XOR-chunk
        _Float16* Al  = SM + 8192;
        _Float16* Bhs = SM + 16384;
        _Float16* Bls = SM + 24576;

        const int bm = byv * 128;
        const int bn = bxv * 128;

        f32x4 acc[2][4] = {};

        float4 ar[4];
        auto aload = [&](int KT) {
            #pragma unroll
            for (int i = 0; i < 4; ++i)
                ar[i] = *(const float4*)(A + (size_t)(bm + (t >> 4) + 32 * i) * DM + KT * 64 + (t & 15) * 4);
        };
        auto awr = [&]() {
            #pragma unroll
            for (int i = 0; i < 4; ++i) {
                int row = (t >> 4) + 32 * i;
                int c4 = t & 15;
                float4 v = ar[i];
                half4 hv, lv;
                hv[0] = (_Float16)v.x; lv[0] = (_Float16)(v.x - (float)hv[0]);
                hv[1] = (_Float16)v.y; lv[1] = (_Float16)(v.y - (float)hv[1]);
                hv[2] = (_Float16)v.z; lv[2] = (_Float16)(v.z - (float)hv[2]);
                hv[3] = (_Float16)v.w; lv[3] = (_Float16)(v.w - (float)hv[3]);
                int off = row * 64 + (((c4 >> 1) ^ (row & 7)) * 8) + (c4 & 1) * 4;
                *(half4*)&Ah[off] = hv;
                *(half4*)&Al[off] = lv;
            }
        };
        auto bgl = [&](int KT) {
            #pragma unroll
            for (int jj = 0; jj < 2; ++jj) {
                int rr = w * 16 + jj * 8 + (lane >> 3);
                const size_t so = (size_t)(bn + rr) * DM + KT * 64 + (lane & 7) * 8;
                gload16(Bh + so, &SM[16384 + (w * 16 + jj * 8) * 64]);
                gload16(Bl + so, &SM[24576 + (w * 16 + jj * 8) * 64]);
            }
        };

        aload(0);
        bgl(0);
        for (int kt = 0; kt < 16; ++kt) {
            awr();
            __syncthreads();
            if (kt < 15) aload(kt + 1);
            #pragma unroll
            for (int ks = 0; ks < 2; ++ks) {
                half8 ah[2], al[2], bh[4], bl[4];
                const int slotx = (ks * 4 + l4g);
                #pragma unroll
                for (int mi = 0; mi < 2; ++mi) {
                    int r = wm + mi * 16 + l15;
                    int off = r * 64 + (slotx ^ (l15 & 7)) * 8;
                    ah[mi] = *(const half8*)&Ah[off];
                    al[mi] = *(const half8*)&Al[off];
                }
                #pragma unroll
                for (int ni = 0; ni < 4; ++ni) {
                    int r = wn + ni * 16 + l15;
                    int off = r * 64 + (slotx ^ (l15 & 7)) * 8;
                    bh[ni] = *(const half8*)&Bhs[off];
                    bl[ni] = *(const half8*)&Bls[off];
                }
                #pragma unroll
                for (int mi = 0; mi < 2; ++mi)
                    #pragma unroll
                    for (int ni = 0; ni < 4; ++ni) {
                        acc[mi][ni] = __builtin_amdgcn_mfma_f32_16x16x32_f16(ah[mi], bh[ni], acc[mi][ni], 0, 0, 0);
                        acc[mi][ni] = __builtin_amdgcn_mfma_f32_16x16x32_f16(ah[mi], bl[ni], acc[mi][ni], 0, 0, 0);
                        acc[mi][ni] = __builtin_amdgcn_mfma_f32_16x16x32_f16(al[mi], bh[ni], acc[mi][ni], 0, 0, 0);
                    }
            }
            __syncthreads();
            if (kt < 15) bgl(kt + 1);
        }

        #pragma unroll
        for (int mi = 0; mi < 2; ++mi)
            #pragma unroll
            for (int ni = 0; ni < 4; ++ni) {
                int col = bn + wn + ni * 16 + l15;
                #pragma unroll
                for (int r = 0; r < 4; ++r) {
                    int row = bm + wm + mi * 16 + l4g * 4 + r;
                    float val = acc[mi][ni][r];
                    _Float16 hv = (_Float16)val;
                    Chi[(size_t)row * DM + col] = hv;
                    Clo[(size_t)row * DM + col] = (_Float16)(val - (float)hv);
                }
            }
    } else {
        // ================= V path (single stream, transposed out) =================
        const int lid2 = lid - 1024;            // 0..511
        const int xcd = lid2 & 7, k2 = lid2 >> 3;
        const int G = xcd * 8 + (k2 >> 3);
        const int bxv = k2 & 7, byv = G;

        _Float16* Ah  = SM;                 // [128][64] XOR-chunk
        _Float16* Bhs = SM + 16384;

        const int bm = byv * 128;
        const int bn = bxv * 128;

        f32x4 acc[2][4] = {};

        float4 ar[4];
        auto aload = [&](int KT) {
            #pragma unroll
            for (int i = 0; i < 4; ++i)
                ar[i] = *(const float4*)(A2 + (size_t)(bm + (t >> 4) + 32 * i) * DM + KT * 64 + (t & 15) * 4);
        };
        auto awr = [&]() {
            #pragma unroll
            for (int i = 0; i < 4; ++i) {
                int row = (t >> 4) + 32 * i;
                int c4 = t & 15;
                float4 v = ar[i];
                half4 hv;
                hv[0] = (_Float16)v.x; hv[1] = (_Float16)v.y;
                hv[2] = (_Float16)v.z; hv[3] = (_Float16)v.w;
                int off = row * 64 + (((c4 >> 1) ^ (row & 7)) * 8) + (c4 & 1) * 4;
                *(half4*)&Ah[off] = hv;
            }
        };
        auto bgl = [&](int KT) {
            #pragma unroll
            for (int jj = 0; jj < 2; ++jj) {
                int rr = w * 16 + jj * 8 + (lane >> 3);
                gload16(Bv + (size_t)(bn + rr) * DM + KT * 64 + (lane & 7) * 8,
                        &SM[16384 + (w * 16 + jj * 8) * 64]);
            }
        };

        aload(0);
        bgl(0);
        for (int kt = 0; kt < 16; ++kt) {
            awr();
            __syncthreads();
            if (kt < 15) aload(kt + 1);
            #pragma unroll
            for (int ks = 0; ks < 2; ++ks) {
                half8 a[2], b[4];
                const int slotx = (ks * 4 + l4g);
                #pragma unroll
                for (int mi = 0; mi < 2; ++mi) {
                    int r = wm + mi * 16 + l15;
                    a[mi] = *(const half8*)&Ah[r * 64 + (slotx ^ (l15 & 7)) * 8];
                }
                #pragma unroll
                for (int ni = 0; ni < 4; ++ni) {
                    int r = wn + ni * 16 + l15;
                    b[ni] = *(const half8*)&Bhs[r * 64 + (slotx ^ (l15 & 7)) * 8];
                }
                #pragma unroll
                for (int mi = 0; mi < 2; ++mi)
                    #pragma unroll
                    for (int ni = 0; ni < 4; ++ni)
                        acc[mi][ni] = __builtin_amdgcn_mfma_f32_16x16x32_f16(a[mi], b[ni], acc[mi][ni], 0, 0, 0);
            }
            __syncthreads();
            if (kt < 15) bgl(kt + 1);
        }

        // transposed epilogue: per-wave [64 n][32 s] tile (pad 34 -> conflict-free)
        _Float16* Tw = SM + w * 2176;   // 64*34
        __syncthreads();                // loop LDS fully consumed
        #pragma unroll
        for (int mi = 0; mi < 2; ++mi)
            #pragma unroll
            for (int ni = 0; ni < 4; ++ni) {
                half4 hv;
                #pragma unroll
                for (int r = 0; r < 4; ++r)
                    hv[r] = (_Float16)acc[mi][ni][r];
                *(half4*)&Tw[(ni * 16 + l15) * 34 + mi * 16 + l4g * 4] = hv;
            }
        __syncthreads();
        {
            const int mg0 = bm + wm;                 // wave's 32 s-rows start
            const int b = mg0 >> 10, s0 = mg0 & 1023;
            _Float16* op = Cv + ((size_t)b * DM + (bn + wn + lane)) * S_ + s0;
            #pragma unroll
            for (int c8 = 0; c8 < 4; ++c8)
                *(half8*)(op + c8 * 8) = *(const half8*)&Tw[lane * 34 + c8 * 8];
        }
    }
}

// ---------------------------------------------------------------------------
// Output projection — r13-validated (dual gload, one barrier), unchanged.
// ---------------------------------------------------------------------------
__global__ __launch_bounds__(256) void gemm_out_k(
    const _Float16* __restrict__ A, const _Float16* __restrict__ Bt,
    float* __restrict__ C, const float* __restrict__ bias)
{
    const int lid = blockIdx.x + 8 * blockIdx.y;
    const int xcd = lid & 7, k2 = lid >> 3;
    const int G = xcd * 8 + (k2 >> 3);
    const int bxv = k2 & 7, byv = G;

    __shared__ __align__(16) _Float16 SM[32768];   // A 2x8192 | B 2x8192

    const int t = threadIdx.x;
    const int lane = t & 63;
    const int w = t >> 6;
    const int wm = (w >> 1) * 64;
    const int wn = (w & 1) * 64;
    const int l15 = lane & 15;
    const int l4g = lane >> 4;

    const int bm = byv * 128;
    const int bn = bxv * 128;

    f32x4 acc[4][4] = {};

    auto stage = [&](int KT, int buf) {
        _Float16* Ad = SM + buf * 8192;
        _Float16* Bd = SM + 16384 + buf * 8192;
        #pragma unroll
        for (int jj = 0; jj < 4; ++jj) {
            int rr = w * 32 + jj * 8 + (lane >> 3);
            const size_t go = (size_t)rr * DM + KT * 64 + (lane & 7) * 8;
            gload16(A + (size_t)bm * DM + go, Ad + (w * 32 + jj * 8) * 64);
            gload16(Bt + (size_t)bn * DM + go, Bd + (w * 32 + jj * 8) * 64);
        }
    };

    stage(0, 0);
    __syncthreads();
    for (int kt = 0; kt < 16; ++kt) {
        const int buf = kt & 1;
        if (kt < 15) stage(kt + 1, buf ^ 1);
        const _Float16* Ac = SM + buf * 8192;
        const _Float16* Bc = SM + 16384 + buf * 8192;
        #pragma unroll
        for (int ks = 0; ks < 2; ++ks) {
            half8 a[4], b[4];
            const int slotx = ks * 4 + l4g;
            #pragma unroll
            for (int mi = 0; mi < 4; ++mi) {
                int row = wm + mi * 16 + l15;
                a[mi] = *(const half8*)&Ac[row * 64 + ((slotx ^ (l15 & 7)) * 8)];
            }
            #pragma unroll
            for (int ni = 0; ni < 4; ++ni) {
                int row = wn + ni * 16 + l15;
                b[ni] = *(const half8*)&Bc[row * 64 + ((slotx ^ (l15 & 7)) * 8)];
            }
            #pragma unroll
            for (int mi = 0; mi < 4; ++mi)
                #pragma unroll
                for (int ni = 0; ni < 4; ++ni)
                    acc[mi][ni] = __builtin_amdgcn_mfma_f32_16x16x32_f16(a[mi], b[ni], acc[mi][ni], 0, 0, 0);
        }
        __syncthreads();
    }

    #pragma unroll
    for (int mi = 0; mi < 4; ++mi)
        #pragma unroll
        for (int ni = 0; ni < 4; ++ni) {
            int col = bn + wn + ni * 16 + l15;
            #pragma unroll
            for (int r = 0; r < 4; ++r) {
                int row = bm + wm + mi * 16 + l4g * 4 + r;
                C[(size_t)row * DM + col] = acc[mi][ni][r] + bias[col];
            }
        }
}

// ---------------------------------------------------------------------------
// Flash attention — r13-validated (single-barrier dbuf, swizzled hh out).
// ---------------------------------------------------------------------------
__global__ __launch_bounds__(256) void attn_k(
    const _Float16* __restrict__ qhg, const _Float16* __restrict__ qlg,
    const _Float16* __restrict__ khg, const _Float16* __restrict__ klg,
    const _Float16* __restrict__ vtg, const unsigned char* __restrict__ maskg,
    const unsigned char* __restrict__ scanp, _Float16* __restrict__ ho)
{
    __shared__ __align__(16) _Float16 KhB[2][64][72];
    __shared__ __align__(16) _Float16 KlB[2][64][72];
    __shared__ __align__(16) _Float16 VtB[2][64][72];

    const int t = threadIdx.x;
    const int lane = t & 63;
    const int w = t >> 6;
    const int l31 = lane & 31;
    const int hi = lane >> 5;

    const int j = blockIdx.y + 16 * blockIdx.z;          // 0..127
    const int head = 16 * blockIdx.x + (j >> 3);         // 0..127
    const int qt = j & 7;
    const int h = head & 15;
    const int b = head >> 4;

    const int colbase = h * DH;
    const int qrow = qt * 128 + w * 32 + l31;

    half8 qfh[4], qfl[4];
    {
        const size_t base = ((size_t)b * S_ + qrow) * DM + colbase;
        #pragma unroll
        for (int ds = 0; ds < 4; ++ds) {
            qfh[ds] = *(const half8*)(qhg + base + ds * 16 + hi * 8);
            qfl[ds] = *(const half8*)(qlg + base + ds * 16 + hi * 8);
        }
    }

    float m_q = -1e30f, ls = 0.0f;
    f32x16 accO0 = {};
    f32x16 accO1 = {};

    const int r0 = t >> 3;
    const int c0 = (t & 7) * 8;
    const _Float16* kph = khg + ((size_t)b * S_) * DM + colbase;
    const _Float16* kpl = klg + ((size_t)b * S_) * DM + colbase;
    const _Float16* vp  = vtg + ((size_t)b * DM + colbase) * S_;
    const unsigned char* sc0 = scanp + (b * 16 + 2 * qt) * 16;
    const unsigned char* sc1 = scanp + (b * 16 + 2 * qt + 1) * 16;

    uint4 akh0, akh1, akl0, akl1, av0, av1;
#define ALOAD(KT) do { \
        akh0 = *(const uint4*)(kph + (size_t)((KT) * 64 + r0) * DM + c0);       \
        akh1 = *(const uint4*)(kph + (size_t)((KT) * 64 + 32 + r0) * DM + c0);  \
        akl0 = *(const uint4*)(kpl + (size_t)((KT) * 64 + r0) * DM + c0);       \
        akl1 = *(const uint4*)(kpl + (size_t)((KT) * 64 + 32 + r0) * DM + c0);  \
        av0  = *(const uint4*)(vp + (size_t)r0 * S_ + (KT) * 64 + c0);          \
        av1  = *(const uint4*)(vp + (size_t)(32 + r0) * S_ + (KT) * 64 + c0);   \
    } while (0)
#define AWRITE(BUF) do { \
        *(uint4*)&KhB[BUF][r0][c0] = akh0; *(uint4*)&KhB[BUF][32 + r0][c0] = akh1; \
        *(uint4*)&KlB[BUF][r0][c0] = akl0; *(uint4*)&KlB[BUF][32 + r0][c0] = akl1; \
        *(uint4*)&VtB[BUF][r0][c0] = av0;  *(uint4*)&VtB[BUF][32 + r0][c0] = av1;  \
    } while (0)

    ALOAD(0);
    AWRITE(0);
    int msk = sc0[0] | sc1[0];

    const float SC = 0.125f * 1.44269504089f;   // scale * log2(e)
    const float THRRAW = 8.0f / SC;             // defer-max threshold (raw)

    for (int kt = 0; kt < 16; ++kt) {
        __syncthreads();                         // buf[cur] visible; buf[cur^1] free
        const int cur = kt & 1;
        const int mskcur = msk;
        if (kt < 15) {
            ALOAD(kt + 1);
            msk = sc0[kt + 1] | sc1[kt + 1];
        }

        f32x16 sa0 = {}, sa1 = {};
        __builtin_amdgcn_s_setprio(1);
        #pragma unroll
        for (int ds = 0; ds < 4; ++ds) {
            half8 kh0 = *(const half8*)&KhB[cur][l31][ds * 16 + hi * 8];
            half8 kl0 = *(const half8*)&KlB[cur][l31][ds * 16 + hi * 8];
            half8 kh1 = *(const half8*)&KhB[cur][32 + l31][ds * 16 + hi * 8];
            half8 kl1 = *(const half8*)&KlB[cur][32 + l31][ds * 16 + hi * 8];
            sa0 = __builtin_amdgcn_mfma_f32_32x32x16_f16(kh0, qfh[ds], sa0, 0, 0, 0);
            sa0 = __builtin_amdgcn_mfma_f32_32x32x16_f16(kh0, qfl[ds], sa0, 0, 0, 0);
            sa0 = __builtin_amdgcn_mfma_f32_32x32x16_f16(kl0, qfh[ds], sa0, 0, 0, 0);
            sa1 = __builtin_amdgcn_mfma_f32_32x32x16_f16(kh1, qfh[ds], sa1, 0, 0, 0);
            sa1 = __builtin_amdgcn_mfma_f32_32x32x16_f16(kh1, qfl[ds], sa1, 0, 0, 0);
            sa1 = __builtin_amdgcn_mfma_f32_32x32x16_f16(kl1, qfh[ds], sa1, 0, 0, 0);
        }
        __builtin_amdgcn_s_setprio(0);

        if (mskcur) {
            const unsigned char* mrow = maskg + ((size_t)b * S_ + qrow) * S_ + kt * 64;
            #pragma unroll
            for (int e = 0; e < 16; ++e) {
                int kl_ = (e & 3) + 8 * (e >> 2) + 4 * hi;
                if (mrow[kl_]) sa0[e] = -1e9f;
                if (mrow[32 + kl_]) sa1[e] = -1e9f;
            }
        }

        float rm = fmaxf(sa0[0], sa0[1]);
        #pragma unroll
        for (int e = 2; e < 16; e += 2) rm = fmaxf(fmaxf(rm, sa0[e]), sa0[e + 1]);
        #pragma unroll
        for (int e = 0; e < 16; e += 2) rm = fmaxf(fmaxf(rm, sa1[e]), sa1[e + 1]);
        rm = fmaxf(rm, __shfl_xor(rm, 32));
        if (__any(rm > m_q + THRRAW)) {
            const float mn = fmaxf(m_q, rm);
            const float sfac = exp2f((m_q - mn) * SC);
            m_q = mn;
            ls *= sfac;
            #pragma unroll
            for (int e = 0; e < 16; ++e) { accO0[e] *= sfac; accO1[e] *= sfac; }
        }
        const float nmn = -m_q * SC;
        float rs = 0.0f;
        #pragma unroll
        for (int e = 0; e < 16; ++e) { sa0[e] = exp2f(fmaf(sa0[e], SC, nmn)); rs += sa0[e]; }
        #pragma unroll
        for (int e = 0; e < 16; ++e) { sa1[e] = exp2f(fmaf(sa1[e], SC, nmn)); rs += sa1[e]; }
        rs += __shfl_xor(rs, 32);
        ls += rs;

        half8 pf[4];
        {
            uint c0_ = pkrtz(sa0[0], sa0[1]),  c1_ = pkrtz(sa0[2], sa0[3]);
            uint c2_ = pkrtz(sa0[4], sa0[5]),  c3_ = pkrtz(sa0[6], sa0[7]);
            uint c4_ = pkrtz(sa0[8], sa0[9]),  c5_ = pkrtz(sa0[10], sa0[11]);
            uint c6_ = pkrtz(sa0[12], sa0[13]), c7_ = pkrtz(sa0[14], sa0[15]);
            PSWAP(c0_, c2_); PSWAP(c1_, c3_);
            PSWAP(c4_, c6_); PSWAP(c5_, c7_);
            uint4 u0 = {c0_, c1_, c2_, c3_}, u1 = {c4_, c5_, c6_, c7_};
            pf[0] = __builtin_bit_cast(half8, u0);
            pf[1] = __builtin_bit_cast(half8, u1);
        }
        {
            uint c0_ = pkrtz(sa1[0], sa1[1]),  c1_ = pkrtz(sa1[2], sa1[3]);
            uint c2_ = pkrtz(sa1[4], sa1[5]),  c3_ = pkrtz(sa1[6], sa1[7]);
            uint c4_ = pkrtz(sa1[8], sa1[9]),  c5_ = pkrtz(sa1[10], sa1[11]);
            uint c6_ = pkrtz(sa1[12], sa1[13]), c7_ = pkrtz(sa1[14], sa1[15]);
            PSWAP(c0_, c2_); PSWAP(c1_, c3_);
            PSWAP(c4_, c6_); PSWAP(c5_, c7_);
            uint4 u0 = {c0_, c1_, c2_, c3_}, u1 = {c4_, c5_, c6_, c7_};
            pf[2] = __builtin_bit_cast(half8, u0);
            pf[3] = __builtin_bit_cast(half8, u1);
        }
        __builtin_amdgcn_s_setprio(1);
        #pragma unroll
        for (int kc = 0; kc < 4; ++kc) {
            half8 vf0 = *(const half8*)&VtB[cur][l31][kc * 16 + hi * 8];
            half8 vf1 = *(const half8*)&VtB[cur][32 + l31][kc * 16 + hi * 8];
            accO0 = __builtin_amdgcn_mfma_f32_32x32x16_f16(vf0, pf[kc], accO0, 0, 0, 0);
            accO1 = __builtin_amdgcn_mfma_f32_32x32x16_f16(vf1, pf[kc], accO1, 0, 0, 0);
        }
        __builtin_amdgcn_s_setprio(0);

        if (kt < 15) AWRITE(cur ^ 1);
    }
#undef ALOAD
#undef AWRITE

    const float inv = 1.0f / ls;
    _Float16* orow = ho + ((size_t)b * S_ + qrow) * DM + colbase;
    const int key = qrow & 7;
    #pragma unroll
    for (int g2 = 0; g2 < 4; ++g2) {
        half4 hv0, hv1;
        #pragma unroll
        for (int e = 0; e < 4; ++e) {
            hv0[e] = (_Float16)(accO0[g2 * 4 + e] * inv);
            hv1[e] = (_Float16)(accO1[g2 * 4 + e] * inv);
        }
        *(half4*)(orow + (g2 ^ key) * 8 + hi * 4) = hv0;
        *(half4*)(orow + ((4 + g2) ^ key) * 8 + hi * 4) = hv1;
    }
}

// ---------------------------------------------------------------------------
extern "C" void kernel_launch(void* const* d_in, const int* in_sizes, int n_in,
                              void* d_out, int out_size, void* d_ws, size_t ws_size,
                              hipStream_t stream)
{
    const float* Qs = (const float*)d_in[0];
    const float* Ks = (const float*)d_in[1];
    const float* Vs = (const float*)d_in[2];
    const unsigned char* mask = (const unsigned char*)d_in[3];
    const float* WQ = (const float*)d_in[4];
    const float* WK = (const float*)d_in[5];
    const float* WV = (const float*)d_in[6];
    const float* WO = (const float*)d_in[7];
    const float* bo = (const float*)d_in[8];

    char* ws = (char*)d_ws;
    const size_t MB = 1024 * 1024;
    _Float16* wqh = (_Float16*)(ws + 0 * MB);
    _Float16* wql = (_Float16*)(ws + 2 * MB);
    _Float16* wkh = (_Float16*)(ws + 4 * MB);
    _Float16* wkl = (_Float16*)(ws + 6 * MB);
    _Float16* wv  = (_Float16*)(ws + 8 * MB);
    _Float16* wo  = (_Float16*)(ws + 10 * MB);
    _Float16* qhi = (_Float16*)(ws + 12 * MB);
    _Float16* qlo = (_Float16*)(ws + 28 * MB);
    _Float16* khi = (_Float16*)(ws + 44 * MB);
    _Float16* klo = (_Float16*)(ws + 60 * MB);
    _Float16* vt  = (_Float16*)(ws + 76 * MB);
    _Float16* hh  = (_Float16*)(ws + 92 * MB);
    unsigned char* scan = (unsigned char*)(ws + 108 * MB);

    prep_k<<<2816, 256, 0, stream>>>(WQ, WK, WV, WO, mask,
                                     wqh, wql, wkh, wkl, wv, wo, scan);

    gemm_qkv_k<<<dim3(8, 64, 3), 512, 0, stream>>>(
        Qs, Ks, Vs, wqh, wql, wkh, wkl, wv,
        qhi, qlo, khi, klo, vt);

    attn_k<<<dim3(8, 16, 8), 256, 0, stream>>>(qhi, qlo, khi, klo, vt, mask, scan, hh);

    gemm_out_k<<<dim3(8, 64), 256, 0, stream>>>(hh, wo, (float*)d_out, bo);
}